// Round 9
// baseline (588.563 us; speedup 1.0000x reference)
//
#include <hip/hip_runtime.h>
#include <math.h>

#define N_NODES 25000
#define N_EDGES 400000
#define HID 128
#define EDGE_F 16
#define ADY 64
#define INNER 160
#define MSG_F 273
#define HEADS 8

// element offsets inside d_out (h2 | coords | res2)
#define OUT_CRD (N_NODES * HID)
#define OUT_RES (N_NODES * (HID + 3))

// ws byte offsets (16-aligned)
#define FLAG_OFF 0
#define DEN_OFF  256
#define CACC_OFF 800256
#define HAGG_OFF 1100288
#define HBF_OFF  13900288            // h as bf16: 3.2M elems = 6.4 MB
#define YBF_OFF  20300288            // y as bf16: 1.6M elems = 3.2 MB
#define BIAS_OFF 23500288            // 6 bias tensors, bf16
#define BW_OFF   23502592            // blocked weights
#define MEMSET_BYTES 13900288

typedef unsigned short u16;
typedef unsigned int u32;
typedef unsigned long long u64;
typedef __attribute__((ext_vector_type(8))) short short8;
typedef __attribute__((ext_vector_type(4))) float f32x4;

__device__ __forceinline__ float bf2f(u16 v) {
    union { u32 u; float f; } x; x.u = ((u32)v) << 16; return x.f;
}
__device__ __forceinline__ u16 f2bf(float f) {
    union { float ff; u32 u; } x; x.ff = f;
    u32 u = x.u;
    u32 rounding = 0x7FFFu + ((u >> 16) & 1u);
    u += rounding;
    return (u16)(u >> 16);
}
__device__ __forceinline__ float silu(float z) {
    z = fminf(fmaxf(z, -30000.f), 30000.f);
    return z / (1.0f + __expf(-z));
}

template<bool F32> __device__ __forceinline__ float ldg1(const void* p, size_t i) {
    if (F32) return ((const float*)p)[i];
    return bf2f(((const u16*)p)[i]);
}
template<bool F32> __device__ __forceinline__ void stg1(void* p, size_t i, float v) {
    if (F32) ((float*)p)[i] = v;
    else     ((u16*)p)[i] = f2bf(v);
}
__device__ __forceinline__ float ldany(const void* p, size_t i, bool f32) {
    return f32 ? ((const float*)p)[i] : bf2f(((const u16*)p)[i]);
}
// wave-level LDS fence (used in node kernel)
__device__ __forceinline__ void wave_lds_fence() {
    __builtin_amdgcn_wave_barrier();
    __builtin_amdgcn_s_waitcnt(0xc07f);   // lgkmcnt(0) only
    __builtin_amdgcn_wave_barrier();
}

// ---------------------------------------------------------------------------
// dtype detector (flag=1 -> fp32 inputs)
// ---------------------------------------------------------------------------
__global__ void detect_kernel(const void* h, int* flag) {
    __shared__ float red[256];
    const int t = threadIdx.x;
    const u16* p = (const u16*)h;
    float mx = 0.f;
    for (int i = 0; i < 8; i++) {
        int idx = (t * 8 + i) * 97;
        float v = fabsf(bf2f(p[idx * 2]));
        mx = fmaxf(mx, v);
    }
    red[t] = mx;
    __syncthreads();
    for (int s = 128; s > 0; s >>= 1) {
        if (t < s) red[t] = fmaxf(red[t], red[t + s]);
        __syncthreads();
    }
    if (t == 0) flag[0] = (red[0] > 1e10f || red[0] == 0.f) ? 1 : 0;
}

// ---------------------------------------------------------------------------
// generic convert list: biases + h + y -> bf16 in ws
// ---------------------------------------------------------------------------
struct CvtArgs {
    const void* src[8];
    u64 dstoff[8];
    int n[8];
};
__global__ void cvt_kernel(const int* __restrict__ flag, char* wsbase, CvtArgs args) {
    const int ten = blockIdx.y;
    const void* s = args.src[ten];
    u16* d = (u16*)(wsbase + args.dstoff[ten]);
    const int n = args.n[ten];
    const bool f32 = (*flag != 0);
    if (f32) {
        const float* sf = (const float*)s;
        for (int i = blockIdx.x * 256 + threadIdx.x; i < n; i += gridDim.x * 256)
            d[i] = f2bf(sf[i]);
    } else {
        const u16* su = (const u16*)s;
        for (int i = blockIdx.x * 256 + threadIdx.x; i < n; i += gridDim.x * 256)
            d[i] = su[i];
    }
}

// ---------------------------------------------------------------------------
// blocked/transposed [n][72] weight builder for all MFMA GEMMs
// ---------------------------------------------------------------------------
__global__ void blockw_kernel(const int* __restrict__ flag, char* ws,
                              u64 b1off, u64 b2off, u64 b3off, u64 b4off,
                              u64 b5off, u64 b6off, u64 b7off, u64 b8off,
                              const void* We1, const void* We2,
                              const void* Wv, const void* Wa, const void* Wc,
                              const void* Wo, const void* Wn1, const void* Wn2,
                              const void* Wf1, const void* Wf2)
{
    const bool f32 = (*flag != 0);
    u16* b1 = (u16*)(ws + b1off);
    u16* b2 = (u16*)(ws + b2off);
    u16* b3 = (u16*)(ws + b3off);
    u16* b4 = (u16*)(ws + b4off);
    u16* b5 = (u16*)(ws + b5off);
    u16* b6 = (u16*)(ws + b6off);
    u16* b7 = (u16*)(ws + b7off);
    u16* b8 = (u16*)(ws + b8off);
    const int g = blockIdx.x * 256 + threadIdx.x;
    const int stride = gridDim.x * 256;
    for (int i = g; i < 5*160*72; i += stride) {
        int c = i / (160*72), rem = i % (160*72), n = rem / 72, kc = rem % 72;
        int k = c*64 + kc;
        float v = 0.f;
        if (kc < 64) {
            if (k < MSG_F)      v = ldany(We1, (size_t)k*INNER + n, f32);
            else if (k == 273)  v = ldany(We1, (size_t)256*INNER + n, f32);
        }
        b1[i] = f2bf(v);
    }
    for (int i = g; i < 3*160*72; i += stride) {
        int c = i / (160*72), rem = i % (160*72), n = rem / 72, kc = rem % 72;
        int k = c*64 + kc;
        float v = 0.f;
        if (kc < 64 && k < INNER) v = ldany(We2, (size_t)k*INNER + n, f32);
        b2[i] = f2bf(v);
    }
    for (int i = g; i < 3*144*72; i += stride) {
        int c = i / (144*72), rem = i % (144*72), n = rem / 72, kc = rem % 72;
        int k = c*64 + kc;
        float v = 0.f;
        if (kc < 64 && k < INNER) {
            if (n < 128)      v = ldany(Wv, (size_t)k*HID + n, f32);
            else if (n < 136) v = ldany(Wa, (size_t)k*HEADS + (n-128), f32);
            else if (n == 136) v = ldany(Wc, (size_t)k, f32);
        }
        b3[i] = f2bf(v);
    }
    for (int i = g; i < 2*128*72; i += stride) {
        int c = i / (128*72), rem = i % (128*72), n = rem / 72, kc = rem % 72;
        int k = c*64 + kc;
        float v = (kc < 64 && k < HID) ? ldany(Wo, (size_t)k*HID + n, f32) : 0.f;
        b4[i] = f2bf(v);
    }
    for (int i = g; i < 2*160*72; i += stride) {
        int c = i / (160*72), rem = i % (160*72), n = rem / 72, kc = rem % 72;
        int k = c*64 + kc;
        float v = (kc < 64) ? ldany(Wn1, (size_t)k*INNER + n, f32) : 0.f;
        b5[i] = f2bf(v);
    }
    for (int i = g; i < 3*128*72; i += stride) {
        int c = i / (128*72), rem = i % (128*72), n = rem / 72, kc = rem % 72;
        int k = c*64 + kc;
        float v = (kc < 64 && k < INNER) ? ldany(Wn2, (size_t)k*HID + n, f32) : 0.f;
        b6[i] = f2bf(v);
    }
    for (int i = g; i < 256*72; i += stride) {
        int n = i / 72, kc = i % 72;
        float v = (kc < 64) ? ldany(Wf1, (size_t)kc*256 + n, f32) : 0.f;
        b7[i] = f2bf(v);
    }
    for (int i = g; i < 256*72; i += stride) {
        int n = i / 72, kc = i % 72;
        float v = (kc < 64) ? ldany(Wf2, (size_t)kc*256 + n, f32) : 0.f;
        b8[i] = f2bf(v);
    }
}

// ---------------------------------------------------------------------------
// MFMA edge kernel: R6 structure (block barriers, cooperative staging), with
// h pre-converted to bf16 (pure uint4 staging, halved gather bytes).
// One 64-edge tile per block. B-fragments from global (L1/L2).
// ---------------------------------------------------------------------------
template<bool F32>   // applies to coords / a only
__device__ __forceinline__ void edge_body(
    const u16* __restrict__ hbf, const void* coords, const void* a,
    const int* __restrict__ src, const int* __restrict__ dst,
    const u16* __restrict__ We1Tb, const u16* __restrict__ We2Tb,
    const u16* __restrict__ W3Tb,
    const u16* __restrict__ cbe1, const u16* __restrict__ cbe2,
    float* __restrict__ den, float* __restrict__ hagg, float* __restrict__ cacc,
    u16* sPool, float* sex, float* sdiff, float* srad, int* ssrc, int* sdstl)
{
    const int t   = threadIdx.x;
    const int w   = t >> 6;
    const int l   = t & 63;
    const int col = l & 15;
    const int q   = l >> 4;
    const int e0  = blockIdx.x * 64;

    u16* sF  = sPool;               // [64][360]
    u16* sM1 = sPool;               // [64][168] (aliases sF)
    u16* sM2 = sPool + 64*168;      // [64][168]

    if (t < 64) {
        int e = e0 + t;
        int s = src[e], d = dst[e];
        ssrc[t] = s; sdstl[t] = d;
        float dx = ldg1<F32>(coords, (size_t)s*3+0) - ldg1<F32>(coords, (size_t)d*3+0);
        float dy = ldg1<F32>(coords, (size_t)s*3+1) - ldg1<F32>(coords, (size_t)d*3+1);
        float dz = ldg1<F32>(coords, (size_t)s*3+2) - ldg1<F32>(coords, (size_t)d*3+2);
        sdiff[t*4+0] = dx; sdiff[t*4+1] = dy; sdiff[t*4+2] = dz;
        float r2 = dx*dx + dy*dy + dz*dz;
        srad[t] = r2;
        sdiff[t*4+3] = 1.0f / (sqrtf(r2 + 1e-5f) + 1.0f);
    }
    __syncthreads();                                    // B1

    // ---- stage ALL f chunks (4 lanes per edge, pure bf16 copies) ----
    {
        int e = t >> 2, part = t & 3;
        int node_s = ssrc[e], node_d = sdstl[e];
        #pragma unroll
        for (int c = 0; c < 4; c++) {
            int node = (c < 2) ? node_s : node_d;
            int c0 = (c & 1) * 64 + part * 16;
            const uint4* gp = (const uint4*)(hbf + (size_t)node*HID + c0);
            *(uint4*)(&sF[e*360 + c*72 + part*16])     = gp[0];
            *(uint4*)(&sF[e*360 + c*72 + part*16 + 8]) = gp[1];
        }
        __align__(16) u16 tmp[16];
        #pragma unroll
        for (int j = 0; j < 16; j++) tmp[j] = 0;
        if (part == 0) {
            float r2 = srad[e];
            tmp[0] = f2bf(r2);                           // kc0 = radial hi
            for (int j = 0; j < 15; j++)
                tmp[1+j] = f2bf(ldg1<F32>(a, (size_t)(e0+e)*EDGE_F + j));
        } else if (part == 1) {
            tmp[0] = f2bf(ldg1<F32>(a, (size_t)(e0+e)*EDGE_F + 15));
            float r2 = srad[e];
            tmp[1] = f2bf(r2 - bf2f(f2bf(r2)));          // kc17 = radial lo
        }
        *(uint4*)(&sF[e*360 + 4*72 + part*16])     = ((uint4*)tmp)[0];
        *(uint4*)(&sF[e*360 + 4*72 + part*16 + 8]) = ((uint4*)tmp)[1];
    }
    __syncthreads();                                    // B2

    // ---- GEMM1: K=320, B from global ----
    f32x4 acc1[10];
    #pragma unroll
    for (int nt = 0; nt < 10; nt++) {
        float v = bf2f(cbe1[nt*16 + col]);
        acc1[nt] = (f32x4){v, v, v, v};
    }
    const u16* fbase = &sF[(w*16 + col)*360];
    #pragma unroll
    for (int c = 0; c < 5; c++) {
        #pragma unroll
        for (int ks = 0; ks < 2; ks++) {
            short8 af = *(const short8*)(fbase + c*72 + ks*32 + q*8);
            const u16* B1 = We1Tb + (size_t)c*160*72 + ks*32 + q*8;
            #pragma unroll
            for (int nt = 0; nt < 10; nt++) {
                short8 b = *(const short8*)(B1 + (nt*16 + col)*72);
                acc1[nt] = __builtin_amdgcn_mfma_f32_16x16x32_bf16(af, b, acc1[nt], 0, 0, 0);
            }
        }
    }
    __syncthreads();                                    // B3 (sF dead)
    #pragma unroll
    for (int nt = 0; nt < 10; nt++)
        #pragma unroll
        for (int r = 0; r < 4; r++)
            sM1[(w*16 + q*4 + r)*168 + nt*16 + col] = f2bf(silu(acc1[nt][r]));
    __syncthreads();                                    // B4

    // ---- GEMM2: K=160 ----
    f32x4 acc2[10];
    #pragma unroll
    for (int nt = 0; nt < 10; nt++) {
        float v = bf2f(cbe2[nt*16 + col]);
        acc2[nt] = (f32x4){v, v, v, v};
    }
    const u16* m1base = &sM1[(w*16 + col)*168];
    #pragma unroll
    for (int k5 = 0; k5 < 5; k5++) {
        short8 af = *(const short8*)(m1base + k5*32 + q*8);
        const u16* B2 = We2Tb + (size_t)(k5>>1)*160*72 + (k5&1)*32 + q*8;
        #pragma unroll
        for (int nt = 0; nt < 10; nt++) {
            short8 b = *(const short8*)(B2 + (nt*16 + col)*72);
            acc2[nt] = __builtin_amdgcn_mfma_f32_16x16x32_bf16(af, b, acc2[nt], 0, 0, 0);
        }
    }
    // sM2 disjoint from sM1 -> no barrier before writes
    #pragma unroll
    for (int nt = 0; nt < 10; nt++)
        #pragma unroll
        for (int r = 0; r < 4; r++)
            sM2[(w*16 + q*4 + r)*168 + nt*16 + col] = f2bf(silu(acc2[nt][r]));
    __syncthreads();                                    // B5

    // ---- GEMM3: N=144, K=160 ----
    f32x4 acc3[9];
    #pragma unroll
    for (int nt = 0; nt < 9; nt++) acc3[nt] = (f32x4){0.f, 0.f, 0.f, 0.f};
    const u16* m2base = &sM2[(w*16 + col)*168];
    #pragma unroll
    for (int k5 = 0; k5 < 5; k5++) {
        short8 af = *(const short8*)(m2base + k5*32 + q*8);
        const u16* B3 = W3Tb + (size_t)(k5>>1)*144*72 + (k5&1)*32 + q*8;
        #pragma unroll
        for (int nt = 0; nt < 9; nt++) {
            short8 b = *(const short8*)(B3 + (nt*16 + col)*72);
            acc3[nt] = __builtin_amdgcn_mfma_f32_16x16x32_bf16(af, b, acc3[nt], 0, 0, 0);
        }
    }

    // ---- epilogue: heads + atomics (R6 style) ----
    const int mbase = w*16 + q*4;
    if (col < 8) {
        #pragma unroll
        for (int r = 0; r < 4; r++) {
            int m = mbase + r;
            int d = sdstl[m];
            float ex = __expf(fminf(fmaxf(acc3[8][r], -30.f), 30.f));
            sex[m*8 + col] = ex;
            atomicAdd(&den[(size_t)d*8 + col], ex);
        }
    } else if (col == 8) {
        #pragma unroll
        for (int r = 0; r < 4; r++) {
            int m = mbase + r;
            int d = sdstl[m];
            float lc = fminf(fmaxf(acc3[8][r], -1e6f), 1e6f);
            float invf = sdiff[m*4 + 3];
            #pragma unroll
            for (int j = 0; j < 3; j++)
                atomicAdd(&cacc[(size_t)d*3 + j], lc * sdiff[m*4 + j] * invf);
        }
    }
    __syncthreads();                                    // B6 (sex visible)
    #pragma unroll
    for (int nt = 0; nt < 8; nt++) {
        #pragma unroll
        for (int r = 0; r < 4; r++) {
            int m = mbase + r;
            int d = sdstl[m];
            atomicAdd(&hagg[(size_t)d*HID + nt*16 + col], acc3[nt][r] * sex[m*8 + nt]);
        }
    }
}

__global__ __launch_bounds__(256, 3)
void edge_kernel(const int* __restrict__ flag,
                 const u16* __restrict__ hbf, const void* coords, const void* a,
                 const int* __restrict__ src, const int* __restrict__ dst,
                 const u16* __restrict__ We1Tb, const u16* __restrict__ We2Tb,
                 const u16* __restrict__ W3Tb,
                 const u16* __restrict__ cbe1, const u16* __restrict__ cbe2,
                 float* __restrict__ den, float* __restrict__ hagg,
                 float* __restrict__ cacc)
{
    __shared__ __align__(16) u16 sPool[64*360];   // 46080 B
    __shared__ float sex[64*8];
    __shared__ float sdiff[64*4];
    __shared__ float srad[64];
    __shared__ int   ssrc[64];
    __shared__ int   sdstl[64];
    if (*flag)
        edge_body<true>(hbf, coords, a, src, dst, We1Tb, We2Tb, W3Tb, cbe1, cbe2,
                        den, hagg, cacc, sPool, sex, sdiff, srad, ssrc, sdstl);
    else
        edge_body<false>(hbf, coords, a, src, dst, We1Tb, We2Tb, W3Tb, cbe1, cbe2,
                         den, hagg, cacc, sPool, sex, sdiff, srad, ssrc, sdstl);
}

// ---------------------------------------------------------------------------
// Barrier-free fused MFMA node kernel; h/y pre-converted bf16.
// ---------------------------------------------------------------------------
template<bool F32>   // applies to res / coords / out
__device__ __forceinline__ void node_body(
    const u16* __restrict__ hbf, const void* res, const void* coords,
    const u16* __restrict__ ybf,
    const float* __restrict__ den, const float* __restrict__ hagg,
    const float* __restrict__ cacc,
    const u16* __restrict__ WoB, const u16* __restrict__ Wn1B,
    const u16* __restrict__ Wn2B, const u16* __restrict__ Wf1B,
    const u16* __restrict__ Wf2B,
    const u16* __restrict__ cbn1, const u16* __restrict__ cbn2,
    const u16* __restrict__ cbf1, const u16* __restrict__ cbf2,
    void* out, u16* sScr)
{
    const int t = threadIdx.x;
    const int w = t >> 6, l = t & 63, col = l & 15, q = l >> 4;
    const int nodew = blockIdx.x * 64 + w * 16;
    const int mynode = nodew + col;
    const bool okA = mynode < N_NODES;
    u16* sc = sScr + w * 16 * 168;

    int gm[4]; bool okC[4];
    #pragma unroll
    for (int r = 0; r < 4; r++) { gm[r] = nodew + q*4 + r; okC[r] = gm[r] < N_NODES; }

    f32x4 aF2[8];
    #pragma unroll
    for (int nt = 0; nt < 8; nt++) aF2[nt] = (f32x4){0.f,0.f,0.f,0.f};
    #pragma unroll
    for (int c = 0; c < 2; c++) {
        #pragma unroll
        for (int ks = 0; ks < 2; ks++) {
            const int kbase = c*64 + ks*32 + q*8;
            union { u16 s[8]; short8 v; } u;
            if (okA) {
                float dd = den[(size_t)mynode*8 + (kbase >> 4)];
                float inv = dd > 0.f ? 1.f/dd : 0.f;
                const float4* gp = (const float4*)(hagg + (size_t)mynode*HID + kbase);
                float4 v0 = gp[0], v1 = gp[1];
                u.s[0]=f2bf(v0.x*inv); u.s[1]=f2bf(v0.y*inv); u.s[2]=f2bf(v0.z*inv); u.s[3]=f2bf(v0.w*inv);
                u.s[4]=f2bf(v1.x*inv); u.s[5]=f2bf(v1.y*inv); u.s[6]=f2bf(v1.z*inv); u.s[7]=f2bf(v1.w*inv);
            } else {
                #pragma unroll
                for (int j = 0; j < 8; j++) u.s[j] = 0;
            }
            const u16* B = WoB + (size_t)c*128*72 + ks*32 + q*8;
            #pragma unroll
            for (int nt = 0; nt < 8; nt++) {
                short8 b = *(const short8*)(B + (nt*16 + col)*72);
                aF2[nt] = __builtin_amdgcn_mfma_f32_16x16x32_bf16(u.v, b, aF2[nt], 0, 0, 0);
            }
        }
    }

    f32x4 aFl[16];
    #pragma unroll
    for (int nt = 0; nt < 16; nt++) {
        float v = bf2f(cbf1[nt*16 + col]);
        aFl[nt] = (f32x4){v,v,v,v};
    }
    #pragma unroll
    for (int ks = 0; ks < 2; ks++) {
        short8 af;
        if (okA) af = *(const short8*)(ybf + (size_t)mynode*ADY + ks*32 + q*8);
        else { union { u16 s[8]; short8 v; } z; for (int j=0;j<8;j++) z.s[j]=0; af = z.v; }
        const u16* B = Wf1B + ks*32 + q*8;
        #pragma unroll
        for (int nt = 0; nt < 16; nt++) {
            short8 b = *(const short8*)(B + (nt*16 + col)*72);
            aFl[nt] = __builtin_amdgcn_mfma_f32_16x16x32_bf16(af, b, aFl[nt], 0, 0, 0);
        }
    }

    float h1c[8][4], r1c[8][4];
    {
        float xv[8][4], s[4], ss[4];
        #pragma unroll
        for (int r = 0; r < 4; r++) { s[r] = 0.f; ss[r] = 0.f; }
        #pragma unroll
        for (int nt = 0; nt < 8; nt++)
            #pragma unroll
            for (int r = 0; r < 4; r++) {
                float hv = okC[r] ? bf2f(hbf[(size_t)gm[r]*HID + nt*16 + col]) : 0.f;
                float x = hv + aF2[nt][r];
                xv[nt][r] = x; s[r] += x; ss[r] += x*x;
            }
        #pragma unroll
        for (int r = 0; r < 4; r++)
            for (int off = 1; off <= 8; off <<= 1) {
                s[r]  += __shfl_xor(s[r], off);
                ss[r] += __shfl_xor(ss[r], off);
            }
        #pragma unroll
        for (int r = 0; r < 4; r++) {
            float mu = s[r] * (1.f/128.f);
            float var = ss[r] * (1.f/128.f) - mu*mu;
            float rs = rsqrtf(fmaxf(var, 0.f) + 1e-5f);
            #pragma unroll
            for (int nt = 0; nt < 8; nt++) {
                float h1 = (xv[nt][r]-mu)*rs*(1.f+aFl[nt][r]) + aFl[nt+8][r];
                h1c[nt][r] = h1;
                float rv = okC[r] ? ldg1<F32>(res, (size_t)gm[r]*HID + nt*16 + col) : 0.f;
                r1c[nt][r] = rv + aF2[nt][r];
                sc[(q*4 + r)*168 + nt*16 + col] = f2bf(h1);
            }
        }
    }
    wave_lds_fence();

    f32x4 aT[10];
    #pragma unroll
    for (int nt = 0; nt < 10; nt++) {
        float v = bf2f(cbn1[nt*16 + col]);
        aT[nt] = (f32x4){v,v,v,v};
    }
    #pragma unroll
    for (int c = 0; c < 2; c++) {
        #pragma unroll
        for (int ks = 0; ks < 2; ks++) {
            short8 af = *(const short8*)(sc + col*168 + c*64 + ks*32 + q*8);
            const u16* B = Wn1B + (size_t)c*160*72 + ks*32 + q*8;
            #pragma unroll
            for (int nt = 0; nt < 10; nt++) {
                short8 b = *(const short8*)(B + (nt*16 + col)*72);
                aT[nt] = __builtin_amdgcn_mfma_f32_16x16x32_bf16(af, b, aT[nt], 0, 0, 0);
            }
        }
    }
    wave_lds_fence();
    #pragma unroll
    for (int nt = 0; nt < 10; nt++)
        #pragma unroll
        for (int r = 0; r < 4; r++)
            sc[(q*4 + r)*168 + nt*16 + col] = f2bf(silu(aT[nt][r]));
    wave_lds_fence();

    f32x4 aF3[8];
    #pragma unroll
    for (int nt = 0; nt < 8; nt++) {
        float v = bf2f(cbn2[nt*16 + col]);
        aF3[nt] = (f32x4){v,v,v,v};
    }
    #pragma unroll
    for (int k5 = 0; k5 < 5; k5++) {
        short8 af = *(const short8*)(sc + col*168 + k5*32 + q*8);
        const u16* B = Wn2B + (size_t)(k5>>1)*128*72 + (k5&1)*32 + q*8;
        #pragma unroll
        for (int nt = 0; nt < 8; nt++) {
            short8 b = *(const short8*)(B + (nt*16 + col)*72);
            aF3[nt] = __builtin_amdgcn_mfma_f32_16x16x32_bf16(af, b, aF3[nt], 0, 0, 0);
        }
    }

    #pragma unroll
    for (int nt = 0; nt < 16; nt++) {
        float v = bf2f(cbf2[nt*16 + col]);
        aFl[nt] = (f32x4){v,v,v,v};
    }
    #pragma unroll
    for (int ks = 0; ks < 2; ks++) {
        short8 af;
        if (okA) af = *(const short8*)(ybf + (size_t)mynode*ADY + ks*32 + q*8);
        else { union { u16 s[8]; short8 v; } z; for (int j=0;j<8;j++) z.s[j]=0; af = z.v; }
        const u16* B = Wf2B + ks*32 + q*8;
        #pragma unroll
        for (int nt = 0; nt < 16; nt++) {
            short8 b = *(const short8*)(B + (nt*16 + col)*72);
            aFl[nt] = __builtin_amdgcn_mfma_f32_16x16x32_bf16(af, b, aFl[nt], 0, 0, 0);
        }
    }

    {
        float xv[8][4], s[4], ss[4];
        #pragma unroll
        for (int r = 0; r < 4; r++) { s[r] = 0.f; ss[r] = 0.f; }
        #pragma unroll
        for (int nt = 0; nt < 8; nt++)
            #pragma unroll
            for (int r = 0; r < 4; r++) {
                float x = h1c[nt][r] + aF3[nt][r];
                xv[nt][r] = x; s[r] += x; ss[r] += x*x;
            }
        #pragma unroll
        for (int r = 0; r < 4; r++)
            for (int off = 1; off <= 8; off <<= 1) {
                s[r]  += __shfl_xor(s[r], off);
                ss[r] += __shfl_xor(ss[r], off);
            }
        #pragma unroll
        for (int r = 0; r < 4; r++) {
            float mu = s[r] * (1.f/128.f);
            float var = ss[r] * (1.f/128.f) - mu*mu;
            float rs = rsqrtf(fmaxf(var, 0.f) + 1e-5f);
            if (okC[r]) {
                #pragma unroll
                for (int nt = 0; nt < 8; nt++) {
                    int n = nt*16 + col;
                    float h2 = (xv[nt][r]-mu)*rs*(1.f+aFl[nt][r]) + aFl[nt+8][r];
                    stg1<F32>(out, (size_t)gm[r]*HID + n, h2);
                    stg1<F32>(out, (size_t)OUT_RES + (size_t)gm[r]*HID + n,
                              r1c[nt][r] + aF3[nt][r]);
                }
            }
        }
    }

    if (q == 0 && okA) {
        #pragma unroll
        for (int j = 0; j < 3; j++)
            stg1<F32>(out, (size_t)OUT_CRD + (size_t)mynode*3 + j,
                      ldg1<F32>(coords, (size_t)mynode*3 + j) + cacc[(size_t)mynode*3 + j]);
    }
}

__global__ __launch_bounds__(256, 2)
void node_kernel(const int* __restrict__ flag,
                 const u16* __restrict__ hbf, const void* res, const void* coords,
                 const u16* __restrict__ ybf,
                 const float* __restrict__ den, const float* __restrict__ hagg,
                 const float* __restrict__ cacc,
                 const u16* __restrict__ WoB, const u16* __restrict__ Wn1B,
                 const u16* __restrict__ Wn2B, const u16* __restrict__ Wf1B,
                 const u16* __restrict__ Wf2B,
                 const u16* __restrict__ cbn1, const u16* __restrict__ cbn2,
                 const u16* __restrict__ cbf1, const u16* __restrict__ cbf2,
                 void* out)
{
    __shared__ __align__(16) u16 sScr[4 * 16 * 168];
    if (*flag)
        node_body<true>(hbf, res, coords, ybf, den, hagg, cacc, WoB, Wn1B, Wn2B,
                        Wf1B, Wf2B, cbn1, cbn2, cbf1, cbf2, out, sScr);
    else
        node_body<false>(hbf, res, coords, ybf, den, hagg, cacc, WoB, Wn1B, Wn2B,
                         Wf1B, Wf2B, cbn1, cbn2, cbf1, cbf2, out, sScr);
}

// ---------------------------------------------------------------------------
extern "C" void kernel_launch(void* const* d_in, const int* in_sizes, int n_in,
                              void* d_out, int out_size, void* d_ws, size_t ws_size,
                              hipStream_t stream)
{
    const void* h      = d_in[0];
    const void* coords = d_in[1];
    const void* a      = d_in[2];
    const void* y      = d_in[3];
    const void* res    = d_in[4];
    const int* src     = (const int*)d_in[5];
    const int* dst     = (const int*)d_in[6];

    char* ws = (char*)d_ws;
    int*   flag = (int*)(ws + FLAG_OFF);
    float* den  = (float*)(ws + DEN_OFF);
    float* cacc = (float*)(ws + CACC_OFF);
    float* hagg = (float*)(ws + HAGG_OFF);
    u16*   hbf  = (u16*)(ws + HBF_OFF);
    u16*   ybf  = (u16*)(ws + YBF_OFF);

    // convert list: 6 biases + h + y
    CvtArgs args;
    const int cvtn[8]   = {160, 160, 160, 128, 256, 256, N_NODES*HID, N_NODES*ADY};
    const int cvtsrc[8] = {8, 10, 16, 18, 20, 22, 0, 3};
    u64 boff[8];
    u64 bo = BIAS_OFF;
    for (int i = 0; i < 6; i++) {
        boff[i] = bo;
        bo += ((u64)cvtn[i] * 2 + 15) & ~(u64)15;
    }
    boff[6] = HBF_OFF;
    boff[7] = YBF_OFF;
    for (int i = 0; i < 8; i++) {
        args.src[i] = d_in[cvtsrc[i]];
        args.dstoff[i] = boff[i];
        args.n[i] = cvtn[i];
    }
    const u16* cbe1 = (const u16*)(ws + boff[0]);
    const u16* cbe2 = (const u16*)(ws + boff[1]);
    const u16* cbn1 = (const u16*)(ws + boff[2]);
    const u16* cbn2 = (const u16*)(ws + boff[3]);
    const u16* cbf1 = (const u16*)(ws + boff[4]);
    const u16* cbf2 = (const u16*)(ws + boff[5]);

    // blocked weights
    u64 bw1 = BW_OFF;
    u64 bw2 = bw1 + (u64)5*160*72*2;
    u64 bw3 = bw2 + (u64)3*160*72*2;
    u64 bw4 = bw3 + (u64)3*144*72*2;
    u64 bw5 = bw4 + (u64)2*128*72*2;
    u64 bw6 = bw5 + (u64)2*160*72*2;
    u64 bw7 = bw6 + (u64)3*128*72*2;
    u64 bw8 = bw7 + (u64)256*72*2;
    const u16* We1Tb = (const u16*)(ws + bw1);
    const u16* We2Tb = (const u16*)(ws + bw2);
    const u16* W3Tb  = (const u16*)(ws + bw3);
    const u16* WoB   = (const u16*)(ws + bw4);
    const u16* Wn1B  = (const u16*)(ws + bw5);
    const u16* Wn2B  = (const u16*)(ws + bw6);
    const u16* Wf1B  = (const u16*)(ws + bw7);
    const u16* Wf2B  = (const u16*)(ws + bw8);

    hipMemsetAsync(d_ws, 0, MEMSET_BYTES, stream);

    detect_kernel<<<1, 256, 0, stream>>>(h, flag);
    cvt_kernel<<<dim3(64, 8), 256, 0, stream>>>(flag, ws, args);
    blockw_kernel<<<128, 256, 0, stream>>>(flag, ws, bw1, bw2, bw3, bw4,
                                           bw5, bw6, bw7, bw8,
                                           d_in[7], d_in[9], d_in[12], d_in[13], d_in[11],
                                           d_in[14], d_in[15], d_in[17], d_in[19], d_in[21]);

    edge_kernel<<<N_EDGES/64, 256, 0, stream>>>(flag, hbf, coords, a, src, dst,
                                                We1Tb, We2Tb, W3Tb, cbe1, cbe2,
                                                den, hagg, cacc);

    node_kernel<<<(N_NODES + 63)/64, 256, 0, stream>>>(
        flag, hbf, res, coords, ybf, den, hagg, cacc,
        WoB, Wn1B, Wn2B, Wf1B, Wf2B, cbn1, cbn2, cbf1, cbf2, d_out);
}

// Round 10
// 539.353 us; speedup vs baseline: 1.0912x; 1.0912x over previous
//
#include <hip/hip_runtime.h>
#include <math.h>

#define N_NODES 25000
#define N_EDGES 400000
#define HID 128
#define EDGE_F 16
#define ADY 64
#define INNER 160
#define MSG_F 273
#define HEADS 8

// element offsets inside d_out (h2 | coords | res2)
#define OUT_CRD (N_NODES * HID)
#define OUT_RES (N_NODES * (HID + 3))

// ws byte offsets (16-aligned)
#define FLAG_OFF 0
#define DEN_OFF  256
#define CACC_OFF 800256
#define HAGG_OFF 1100288
#define HBF_OFF  13900288            // h as bf16: 6.4 MB
#define YBF_OFF  20300288            // y as bf16: 3.2 MB
#define BIAS_OFF 23500288            // 6 bias tensors, bf16
#define BW_OFF   23502592            // blocked weights
#define MEMSET_BYTES 13900288

typedef unsigned short u16;
typedef unsigned int u32;
typedef unsigned long long u64;
typedef __attribute__((ext_vector_type(8))) short short8;
typedef __attribute__((ext_vector_type(4))) float f32x4;

__device__ __forceinline__ float bf2f(u16 v) {
    union { u32 u; float f; } x; x.u = ((u32)v) << 16; return x.f;
}
__device__ __forceinline__ u16 f2bf(float f) {
    union { float ff; u32 u; } x; x.ff = f;
    u32 u = x.u;
    u32 rounding = 0x7FFFu + ((u >> 16) & 1u);
    u += rounding;
    return (u16)(u >> 16);
}
__device__ __forceinline__ float silu(float z) {
    z = fminf(fmaxf(z, -30000.f), 30000.f);
    return z / (1.0f + __expf(-z));
}

template<bool F32> __device__ __forceinline__ float ldg1(const void* p, size_t i) {
    if (F32) return ((const float*)p)[i];
    return bf2f(((const u16*)p)[i]);
}
template<bool F32> __device__ __forceinline__ void stg1(void* p, size_t i, float v) {
    if (F32) ((float*)p)[i] = v;
    else     ((u16*)p)[i] = f2bf(v);
}
__device__ __forceinline__ float ldany(const void* p, size_t i, bool f32) {
    return f32 ? ((const float*)p)[i] : bf2f(((const u16*)p)[i]);
}
// wave-level LDS fence (node kernel)
__device__ __forceinline__ void wave_lds_fence() {
    __builtin_amdgcn_wave_barrier();
    __builtin_amdgcn_s_waitcnt(0xc07f);   // lgkmcnt(0) only
    __builtin_amdgcn_wave_barrier();
}

// ---------------------------------------------------------------------------
// Fused preprocessing: per-block dtype detect (deterministic) + cvt + blockw.
// ---------------------------------------------------------------------------
struct CvtArgs {
    const void* src[8];
    u64 dstoff[8];
    int n[8];
};
struct BwArgs {
    const void* We1; const void* We2; const void* Wv; const void* Wa;
    const void* Wc;  const void* Wo;  const void* Wn1; const void* Wn2;
    const void* Wf1; const void* Wf2;
    u64 b1, b2, b3, b4, b5, b6, b7, b8;
};

__global__ __launch_bounds__(256)
void preproc_kernel(const void* hsrc, int* flag, char* ws, CvtArgs args, BwArgs bwa)
{
    __shared__ float red[256];
    __shared__ int sflag;
    const int t = threadIdx.x;
    // ---- local detect ----
    {
        const u16* p = (const u16*)hsrc;
        float mx = 0.f;
        for (int i = 0; i < 8; i++) {
            int idx = (t * 8 + i) * 97;
            float v = fabsf(bf2f(p[idx * 2]));
            mx = fmaxf(mx, v);
        }
        red[t] = mx;
        __syncthreads();
        for (int s = 128; s > 0; s >>= 1) {
            if (t < s) red[t] = fmaxf(red[t], red[t + s]);
            __syncthreads();
        }
        if (t == 0) {
            sflag = (red[0] > 1e10f || red[0] == 0.f) ? 1 : 0;
            if (blockIdx.x == 0) flag[0] = sflag;
        }
        __syncthreads();
    }
    const bool f32 = (sflag != 0);
    const int g = blockIdx.x * 256 + t;
    const int stride = gridDim.x * 256;

    // ---- cvt: biases + h + y ----
    for (int ten = 0; ten < 8; ten++) {
        const void* s = args.src[ten];
        u16* d = (u16*)(ws + args.dstoff[ten]);
        const int n = args.n[ten];
        if (f32) {
            const float* sf = (const float*)s;
            for (int i = g; i < n; i += stride) d[i] = f2bf(sf[i]);
        } else {
            const u16* su = (const u16*)s;
            for (int i = g; i < n; i += stride) d[i] = su[i];
        }
    }

    // ---- blockw ----
    u16* b1 = (u16*)(ws + bwa.b1);
    u16* b2 = (u16*)(ws + bwa.b2);
    u16* b3 = (u16*)(ws + bwa.b3);
    u16* b4 = (u16*)(ws + bwa.b4);
    u16* b5 = (u16*)(ws + bwa.b5);
    u16* b6 = (u16*)(ws + bwa.b6);
    u16* b7 = (u16*)(ws + bwa.b7);
    u16* b8 = (u16*)(ws + bwa.b8);
    for (int i = g; i < 5*160*72; i += stride) {
        int c = i / (160*72), rem = i % (160*72), n = rem / 72, kc = rem % 72;
        int k = c*64 + kc;
        float v = 0.f;
        if (kc < 64) {
            if (k < MSG_F)      v = ldany(bwa.We1, (size_t)k*INNER + n, f32);
            else if (k == 273)  v = ldany(bwa.We1, (size_t)256*INNER + n, f32);
        }
        b1[i] = f2bf(v);
    }
    for (int i = g; i < 3*160*72; i += stride) {
        int c = i / (160*72), rem = i % (160*72), n = rem / 72, kc = rem % 72;
        int k = c*64 + kc;
        float v = 0.f;
        if (kc < 64 && k < INNER) v = ldany(bwa.We2, (size_t)k*INNER + n, f32);
        b2[i] = f2bf(v);
    }
    for (int i = g; i < 3*144*72; i += stride) {
        int c = i / (144*72), rem = i % (144*72), n = rem / 72, kc = rem % 72;
        int k = c*64 + kc;
        float v = 0.f;
        if (kc < 64 && k < INNER) {
            if (n < 128)      v = ldany(bwa.Wv, (size_t)k*HID + n, f32);
            else if (n < 136) v = ldany(bwa.Wa, (size_t)k*HEADS + (n-128), f32);
            else if (n == 136) v = ldany(bwa.Wc, (size_t)k, f32);
        }
        b3[i] = f2bf(v);
    }
    for (int i = g; i < 2*128*72; i += stride) {
        int c = i / (128*72), rem = i % (128*72), n = rem / 72, kc = rem % 72;
        int k = c*64 + kc;
        float v = (kc < 64 && k < HID) ? ldany(bwa.Wo, (size_t)k*HID + n, f32) : 0.f;
        b4[i] = f2bf(v);
    }
    for (int i = g; i < 2*160*72; i += stride) {
        int c = i / (160*72), rem = i % (160*72), n = rem / 72, kc = rem % 72;
        int k = c*64 + kc;
        float v = (kc < 64) ? ldany(bwa.Wn1, (size_t)k*INNER + n, f32) : 0.f;
        b5[i] = f2bf(v);
    }
    for (int i = g; i < 3*128*72; i += stride) {
        int c = i / (128*72), rem = i % (128*72), n = rem / 72, kc = rem % 72;
        int k = c*64 + kc;
        float v = (kc < 64 && k < INNER) ? ldany(bwa.Wn2, (size_t)k*HID + n, f32) : 0.f;
        b6[i] = f2bf(v);
    }
    for (int i = g; i < 256*72; i += stride) {
        int n = i / 72, kc = i % 72;
        float v = (kc < 64) ? ldany(bwa.Wf1, (size_t)kc*256 + n, f32) : 0.f;
        b7[i] = f2bf(v);
    }
    for (int i = g; i < 256*72; i += stride) {
        int n = i / 72, kc = i % 72;
        float v = (kc < 64) ? ldany(bwa.Wf2, (size_t)kc*256 + n, f32) : 0.f;
        b8[i] = f2bf(v);
    }
}

// ---------------------------------------------------------------------------
// MFMA edge kernel (R9 structure): cooperative bf16 staging, block barriers
// B1-B5, shfl-based ex exchange (no post-atomic barrier), c=4 ks=1 skipped
// (all-zero K slots). B-fragments from global (L1/L2).
// ---------------------------------------------------------------------------
template<bool F32>   // applies to coords / a only
__device__ __forceinline__ void edge_body(
    const u16* __restrict__ hbf, const void* coords, const void* a,
    const int* __restrict__ src, const int* __restrict__ dst,
    const u16* __restrict__ We1Tb, const u16* __restrict__ We2Tb,
    const u16* __restrict__ W3Tb,
    const u16* __restrict__ cbe1, const u16* __restrict__ cbe2,
    float* __restrict__ den, float* __restrict__ hagg, float* __restrict__ cacc,
    u16* sPool, float* sdiff, float* srad, int* ssrc, int* sdstl)
{
    const int t   = threadIdx.x;
    const int w   = t >> 6;
    const int l   = t & 63;
    const int col = l & 15;
    const int q   = l >> 4;
    const int e0  = blockIdx.x * 64;

    u16* sF  = sPool;               // [64][360]
    u16* sM1 = sPool;               // [64][168] (aliases sF)
    u16* sM2 = sPool + 64*168;      // [64][168]

    if (t < 64) {
        int e = e0 + t;
        int s = src[e], d = dst[e];
        ssrc[t] = s; sdstl[t] = d;
        float dx = ldg1<F32>(coords, (size_t)s*3+0) - ldg1<F32>(coords, (size_t)d*3+0);
        float dy = ldg1<F32>(coords, (size_t)s*3+1) - ldg1<F32>(coords, (size_t)d*3+1);
        float dz = ldg1<F32>(coords, (size_t)s*3+2) - ldg1<F32>(coords, (size_t)d*3+2);
        sdiff[t*4+0] = dx; sdiff[t*4+1] = dy; sdiff[t*4+2] = dz;
        float r2 = dx*dx + dy*dy + dz*dz;
        srad[t] = r2;
        sdiff[t*4+3] = 1.0f / (sqrtf(r2 + 1e-5f) + 1.0f);
    }
    __syncthreads();                                    // B1

    // ---- stage ALL f chunks (4 lanes per edge, pure bf16 copies) ----
    {
        int e = t >> 2, part = t & 3;
        int node_s = ssrc[e], node_d = sdstl[e];
        #pragma unroll
        for (int c = 0; c < 4; c++) {
            int node = (c < 2) ? node_s : node_d;
            int c0 = (c & 1) * 64 + part * 16;
            const uint4* gp = (const uint4*)(hbf + (size_t)node*HID + c0);
            *(uint4*)(&sF[e*360 + c*72 + part*16])     = gp[0];
            *(uint4*)(&sF[e*360 + c*72 + part*16 + 8]) = gp[1];
        }
        // feature chunk: only kc 0..31 used (ks=1 skipped in GEMM1)
        if (part < 2) {
            __align__(16) u16 tmp[16];
            #pragma unroll
            for (int j = 0; j < 16; j++) tmp[j] = 0;
            if (part == 0) {
                float r2 = srad[e];
                tmp[0] = f2bf(r2);                           // kc0 = radial hi
                for (int j = 0; j < 15; j++)
                    tmp[1+j] = f2bf(ldg1<F32>(a, (size_t)(e0+e)*EDGE_F + j));
            } else {
                tmp[0] = f2bf(ldg1<F32>(a, (size_t)(e0+e)*EDGE_F + 15));
                float r2 = srad[e];
                tmp[1] = f2bf(r2 - bf2f(f2bf(r2)));          // kc17 = radial lo
            }
            *(uint4*)(&sF[e*360 + 4*72 + part*16])     = ((uint4*)tmp)[0];
            *(uint4*)(&sF[e*360 + 4*72 + part*16 + 8]) = ((uint4*)tmp)[1];
        }
    }
    __syncthreads();                                    // B2

    // ---- GEMM1: K=288 effective (4 chunks x2 ks + c4 ks0) ----
    f32x4 acc1[10];
    #pragma unroll
    for (int nt = 0; nt < 10; nt++) {
        float v = bf2f(cbe1[nt*16 + col]);
        acc1[nt] = (f32x4){v, v, v, v};
    }
    const u16* fbase = &sF[(w*16 + col)*360];
    #pragma unroll
    for (int c = 0; c < 4; c++) {
        #pragma unroll
        for (int ks = 0; ks < 2; ks++) {
            short8 af = *(const short8*)(fbase + c*72 + ks*32 + q*8);
            const u16* B1 = We1Tb + (size_t)c*160*72 + ks*32 + q*8;
            #pragma unroll
            for (int nt = 0; nt < 10; nt++) {
                short8 b = *(const short8*)(B1 + (nt*16 + col)*72);
                acc1[nt] = __builtin_amdgcn_mfma_f32_16x16x32_bf16(af, b, acc1[nt], 0, 0, 0);
            }
        }
    }
    {   // c=4, ks=0 only (kc 32..63 are all-zero on A and B)
        short8 af = *(const short8*)(fbase + 4*72 + q*8);
        const u16* B1 = We1Tb + (size_t)4*160*72 + q*8;
        #pragma unroll
        for (int nt = 0; nt < 10; nt++) {
            short8 b = *(const short8*)(B1 + (nt*16 + col)*72);
            acc1[nt] = __builtin_amdgcn_mfma_f32_16x16x32_bf16(af, b, acc1[nt], 0, 0, 0);
        }
    }
    __syncthreads();                                    // B3 (sF dead)
    #pragma unroll
    for (int nt = 0; nt < 10; nt++)
        #pragma unroll
        for (int r = 0; r < 4; r++)
            sM1[(w*16 + q*4 + r)*168 + nt*16 + col] = f2bf(silu(acc1[nt][r]));
    __syncthreads();                                    // B4

    // ---- GEMM2: K=160 ----
    f32x4 acc2[10];
    #pragma unroll
    for (int nt = 0; nt < 10; nt++) {
        float v = bf2f(cbe2[nt*16 + col]);
        acc2[nt] = (f32x4){v, v, v, v};
    }
    const u16* m1base = &sM1[(w*16 + col)*168];
    #pragma unroll
    for (int k5 = 0; k5 < 5; k5++) {
        short8 af = *(const short8*)(m1base + k5*32 + q*8);
        const u16* B2 = We2Tb + (size_t)(k5>>1)*160*72 + (k5&1)*32 + q*8;
        #pragma unroll
        for (int nt = 0; nt < 10; nt++) {
            short8 b = *(const short8*)(B2 + (nt*16 + col)*72);
            acc2[nt] = __builtin_amdgcn_mfma_f32_16x16x32_bf16(af, b, acc2[nt], 0, 0, 0);
        }
    }
    #pragma unroll
    for (int nt = 0; nt < 10; nt++)
        #pragma unroll
        for (int r = 0; r < 4; r++)
            sM2[(w*16 + q*4 + r)*168 + nt*16 + col] = f2bf(silu(acc2[nt][r]));
    __syncthreads();                                    // B5

    // ---- GEMM3: N=144, K=160 ----
    f32x4 acc3[9];
    #pragma unroll
    for (int nt = 0; nt < 9; nt++) acc3[nt] = (f32x4){0.f, 0.f, 0.f, 0.f};
    const u16* m2base = &sM2[(w*16 + col)*168];
    #pragma unroll
    for (int k5 = 0; k5 < 5; k5++) {
        short8 af = *(const short8*)(m2base + k5*32 + q*8);
        const u16* B3 = W3Tb + (size_t)(k5>>1)*144*72 + (k5&1)*32 + q*8;
        #pragma unroll
        for (int nt = 0; nt < 9; nt++) {
            short8 b = *(const short8*)(B3 + (nt*16 + col)*72);
            acc3[nt] = __builtin_amdgcn_mfma_f32_16x16x32_bf16(af, b, acc3[nt], 0, 0, 0);
        }
    }

    // ---- epilogue: wave-local, no barrier ----
    int dstep[4];
    #pragma unroll
    for (int r = 0; r < 4; r++) dstep[r] = sdstl[w*16 + q*4 + r];

    float exv[4] = {0.f, 0.f, 0.f, 0.f};
    if (col < 8) {           // logits: head=col
        #pragma unroll
        for (int r = 0; r < 4; r++) {
            float ex = __expf(fminf(fmaxf(acc3[8][r], -30.f), 30.f));
            exv[r] = ex;
            atomicAdd(&den[(size_t)dstep[r]*8 + col], ex);
        }
    } else if (col == 8) {   // coord scalar
        #pragma unroll
        for (int r = 0; r < 4; r++) {
            int idx = w*16 + q*4 + r;
            int dd = dstep[r];
            float invf = sdiff[idx*4 + 3];
            float lc = fminf(fmaxf(acc3[8][r], -1e6f), 1e6f) * invf;
            #pragma unroll
            for (int j = 0; j < 3; j++)
                atomicAdd(&cacc[(size_t)dd*3 + j], lc * sdiff[idx*4 + j]);
        }
    }
    // ex via shfl: source lane q*16+nt holds head nt for rows q*4+r
    #pragma unroll
    for (int nt = 0; nt < 8; nt++) {
        float ex0 = __shfl(exv[0], q*16 + nt);
        float ex1 = __shfl(exv[1], q*16 + nt);
        float ex2 = __shfl(exv[2], q*16 + nt);
        float ex3 = __shfl(exv[3], q*16 + nt);
        atomicAdd(&hagg[(size_t)dstep[0]*HID + nt*16 + col], acc3[nt][0] * ex0);
        atomicAdd(&hagg[(size_t)dstep[1]*HID + nt*16 + col], acc3[nt][1] * ex1);
        atomicAdd(&hagg[(size_t)dstep[2]*HID + nt*16 + col], acc3[nt][2] * ex2);
        atomicAdd(&hagg[(size_t)dstep[3]*HID + nt*16 + col], acc3[nt][3] * ex3);
    }
}

__global__ __launch_bounds__(256, 3)
void edge_kernel(const int* __restrict__ flag,
                 const u16* __restrict__ hbf, const void* coords, const void* a,
                 const int* __restrict__ src, const int* __restrict__ dst,
                 const u16* __restrict__ We1Tb, const u16* __restrict__ We2Tb,
                 const u16* __restrict__ W3Tb,
                 const u16* __restrict__ cbe1, const u16* __restrict__ cbe2,
                 float* __restrict__ den, float* __restrict__ hagg,
                 float* __restrict__ cacc)
{
    __shared__ __align__(16) u16 sPool[64*360];   // 46080 B
    __shared__ float sdiff[64*4];
    __shared__ float srad[64];
    __shared__ int   ssrc[64];
    __shared__ int   sdstl[64];
    if (*flag)
        edge_body<true>(hbf, coords, a, src, dst, We1Tb, We2Tb, W3Tb, cbe1, cbe2,
                        den, hagg, cacc, sPool, sdiff, srad, ssrc, sdstl);
    else
        edge_body<false>(hbf, coords, a, src, dst, We1Tb, We2Tb, W3Tb, cbe1, cbe2,
                         den, hagg, cacc, sPool, sdiff, srad, ssrc, sdstl);
}

// ---------------------------------------------------------------------------
// Barrier-free fused MFMA node kernel (unchanged from R9)
// ---------------------------------------------------------------------------
template<bool F32>   // applies to res / coords / out
__device__ __forceinline__ void node_body(
    const u16* __restrict__ hbf, const void* res, const void* coords,
    const u16* __restrict__ ybf,
    const float* __restrict__ den, const float* __restrict__ hagg,
    const float* __restrict__ cacc,
    const u16* __restrict__ WoB, const u16* __restrict__ Wn1B,
    const u16* __restrict__ Wn2B, const u16* __restrict__ Wf1B,
    const u16* __restrict__ Wf2B,
    const u16* __restrict__ cbn1, const u16* __restrict__ cbn2,
    const u16* __restrict__ cbf1, const u16* __restrict__ cbf2,
    void* out, u16* sScr)
{
    const int t = threadIdx.x;
    const int w = t >> 6, l = t & 63, col = l & 15, q = l >> 4;
    const int nodew = blockIdx.x * 64 + w * 16;
    const int mynode = nodew + col;
    const bool okA = mynode < N_NODES;
    u16* sc = sScr + w * 16 * 168;

    int gm[4]; bool okC[4];
    #pragma unroll
    for (int r = 0; r < 4; r++) { gm[r] = nodew + q*4 + r; okC[r] = gm[r] < N_NODES; }

    f32x4 aF2[8];
    #pragma unroll
    for (int nt = 0; nt < 8; nt++) aF2[nt] = (f32x4){0.f,0.f,0.f,0.f};
    #pragma unroll
    for (int c = 0; c < 2; c++) {
        #pragma unroll
        for (int ks = 0; ks < 2; ks++) {
            const int kbase = c*64 + ks*32 + q*8;
            union { u16 s[8]; short8 v; } u;
            if (okA) {
                float dd = den[(size_t)mynode*8 + (kbase >> 4)];
                float inv = dd > 0.f ? 1.f/dd : 0.f;
                const float4* gp = (const float4*)(hagg + (size_t)mynode*HID + kbase);
                float4 v0 = gp[0], v1 = gp[1];
                u.s[0]=f2bf(v0.x*inv); u.s[1]=f2bf(v0.y*inv); u.s[2]=f2bf(v0.z*inv); u.s[3]=f2bf(v0.w*inv);
                u.s[4]=f2bf(v1.x*inv); u.s[5]=f2bf(v1.y*inv); u.s[6]=f2bf(v1.z*inv); u.s[7]=f2bf(v1.w*inv);
            } else {
                #pragma unroll
                for (int j = 0; j < 8; j++) u.s[j] = 0;
            }
            const u16* B = WoB + (size_t)c*128*72 + ks*32 + q*8;
            #pragma unroll
            for (int nt = 0; nt < 8; nt++) {
                short8 b = *(const short8*)(B + (nt*16 + col)*72);
                aF2[nt] = __builtin_amdgcn_mfma_f32_16x16x32_bf16(u.v, b, aF2[nt], 0, 0, 0);
            }
        }
    }

    f32x4 aFl[16];
    #pragma unroll
    for (int nt = 0; nt < 16; nt++) {
        float v = bf2f(cbf1[nt*16 + col]);
        aFl[nt] = (f32x4){v,v,v,v};
    }
    #pragma unroll
    for (int ks = 0; ks < 2; ks++) {
        short8 af;
        if (okA) af = *(const short8*)(ybf + (size_t)mynode*ADY + ks*32 + q*8);
        else { union { u16 s[8]; short8 v; } z; for (int j=0;j<8;j++) z.s[j]=0; af = z.v; }
        const u16* B = Wf1B + ks*32 + q*8;
        #pragma unroll
        for (int nt = 0; nt < 16; nt++) {
            short8 b = *(const short8*)(B + (nt*16 + col)*72);
            aFl[nt] = __builtin_amdgcn_mfma_f32_16x16x32_bf16(af, b, aFl[nt], 0, 0, 0);
        }
    }

    float h1c[8][4], r1c[8][4];
    {
        float xv[8][4], s[4], ss[4];
        #pragma unroll
        for (int r = 0; r < 4; r++) { s[r] = 0.f; ss[r] = 0.f; }
        #pragma unroll
        for (int nt = 0; nt < 8; nt++)
            #pragma unroll
            for (int r = 0; r < 4; r++) {
                float hv = okC[r] ? bf2f(hbf[(size_t)gm[r]*HID + nt*16 + col]) : 0.f;
                float x = hv + aF2[nt][r];
                xv[nt][r] = x; s[r] += x; ss[r] += x*x;
            }
        #pragma unroll
        for (int r = 0; r < 4; r++)
            for (int off = 1; off <= 8; off <<= 1) {
                s[r]  += __shfl_xor(s[r], off);
                ss[r] += __shfl_xor(ss[r], off);
            }
        #pragma unroll
        for (int r = 0; r < 4; r++) {
            float mu = s[r] * (1.f/128.f);
            float var = ss[r] * (1.f/128.f) - mu*mu;
            float rs = rsqrtf(fmaxf(var, 0.f) + 1e-5f);
            #pragma unroll
            for (int nt = 0; nt < 8; nt++) {
                float h1 = (xv[nt][r]-mu)*rs*(1.f+aFl[nt][r]) + aFl[nt+8][r];
                h1c[nt][r] = h1;
                float rv = okC[r] ? ldg1<F32>(res, (size_t)gm[r]*HID + nt*16 + col) : 0.f;
                r1c[nt][r] = rv + aF2[nt][r];
                sc[(q*4 + r)*168 + nt*16 + col] = f2bf(h1);
            }
        }
    }
    wave_lds_fence();

    f32x4 aT[10];
    #pragma unroll
    for (int nt = 0; nt < 10; nt++) {
        float v = bf2f(cbn1[nt*16 + col]);
        aT[nt] = (f32x4){v,v,v,v};
    }
    #pragma unroll
    for (int c = 0; c < 2; c++) {
        #pragma unroll
        for (int ks = 0; ks < 2; ks++) {
            short8 af = *(const short8*)(sc + col*168 + c*64 + ks*32 + q*8);
            const u16* B = Wn1B + (size_t)c*160*72 + ks*32 + q*8;
            #pragma unroll
            for (int nt = 0; nt < 10; nt++) {
                short8 b = *(const short8*)(B + (nt*16 + col)*72);
                aT[nt] = __builtin_amdgcn_mfma_f32_16x16x32_bf16(af, b, aT[nt], 0, 0, 0);
            }
        }
    }
    wave_lds_fence();
    #pragma unroll
    for (int nt = 0; nt < 10; nt++)
        #pragma unroll
        for (int r = 0; r < 4; r++)
            sc[(q*4 + r)*168 + nt*16 + col] = f2bf(silu(aT[nt][r]));
    wave_lds_fence();

    f32x4 aF3[8];
    #pragma unroll
    for (int nt = 0; nt < 8; nt++) {
        float v = bf2f(cbn2[nt*16 + col]);
        aF3[nt] = (f32x4){v,v,v,v};
    }
    #pragma unroll
    for (int k5 = 0; k5 < 5; k5++) {
        short8 af = *(const short8*)(sc + col*168 + k5*32 + q*8);
        const u16* B = Wn2B + (size_t)(k5>>1)*128*72 + (k5&1)*32 + q*8;
        #pragma unroll
        for (int nt = 0; nt < 8; nt++) {
            short8 b = *(const short8*)(B + (nt*16 + col)*72);
            aF3[nt] = __builtin_amdgcn_mfma_f32_16x16x32_bf16(af, b, aF3[nt], 0, 0, 0);
        }
    }

    #pragma unroll
    for (int nt = 0; nt < 16; nt++) {
        float v = bf2f(cbf2[nt*16 + col]);
        aFl[nt] = (f32x4){v,v,v,v};
    }
    #pragma unroll
    for (int ks = 0; ks < 2; ks++) {
        short8 af;
        if (okA) af = *(const short8*)(ybf + (size_t)mynode*ADY + ks*32 + q*8);
        else { union { u16 s[8]; short8 v; } z; for (int j=0;j<8;j++) z.s[j]=0; af = z.v; }
        const u16* B = Wf2B + ks*32 + q*8;
        #pragma unroll
        for (int nt = 0; nt < 16; nt++) {
            short8 b = *(const short8*)(B + (nt*16 + col)*72);
            aFl[nt] = __builtin_amdgcn_mfma_f32_16x16x32_bf16(af, b, aFl[nt], 0, 0, 0);
        }
    }

    {
        float xv[8][4], s[4], ss[4];
        #pragma unroll
        for (int r = 0; r < 4; r++) { s[r] = 0.f; ss[r] = 0.f; }
        #pragma unroll
        for (int nt = 0; nt < 8; nt++)
            #pragma unroll
            for (int r = 0; r < 4; r++) {
                float x = h1c[nt][r] + aF3[nt][r];
                xv[nt][r] = x; s[r] += x; ss[r] += x*x;
            }
        #pragma unroll
        for (int r = 0; r < 4; r++)
            for (int off = 1; off <= 8; off <<= 1) {
                s[r]  += __shfl_xor(s[r], off);
                ss[r] += __shfl_xor(ss[r], off);
            }
        #pragma unroll
        for (int r = 0; r < 4; r++) {
            float mu = s[r] * (1.f/128.f);
            float var = ss[r] * (1.f/128.f) - mu*mu;
            float rs = rsqrtf(fmaxf(var, 0.f) + 1e-5f);
            if (okC[r]) {
                #pragma unroll
                for (int nt = 0; nt < 8; nt++) {
                    int n = nt*16 + col;
                    float h2 = (xv[nt][r]-mu)*rs*(1.f+aFl[nt][r]) + aFl[nt+8][r];
                    stg1<F32>(out, (size_t)gm[r]*HID + n, h2);
                    stg1<F32>(out, (size_t)OUT_RES + (size_t)gm[r]*HID + n,
                              r1c[nt][r] + aF3[nt][r]);
                }
            }
        }
    }

    if (q == 0 && okA) {
        #pragma unroll
        for (int j = 0; j < 3; j++)
            stg1<F32>(out, (size_t)OUT_CRD + (size_t)mynode*3 + j,
                      ldg1<F32>(coords, (size_t)mynode*3 + j) + cacc[(size_t)mynode*3 + j]);
    }
}

__global__ __launch_bounds__(256, 2)
void node_kernel(const int* __restrict__ flag,
                 const u16* __restrict__ hbf, const void* res, const void* coords,
                 const u16* __restrict__ ybf,
                 const float* __restrict__ den, const float* __restrict__ hagg,
                 const float* __restrict__ cacc,
                 const u16* __restrict__ WoB, const u16* __restrict__ Wn1B,
                 const u16* __restrict__ Wn2B, const u16* __restrict__ Wf1B,
                 const u16* __restrict__ Wf2B,
                 const u16* __restrict__ cbn1, const u16* __restrict__ cbn2,
                 const u16* __restrict__ cbf1, const u16* __restrict__ cbf2,
                 void* out)
{
    __shared__ __align__(16) u16 sScr[4 * 16 * 168];
    if (*flag)
        node_body<true>(hbf, res, coords, ybf, den, hagg, cacc, WoB, Wn1B, Wn2B,
                        Wf1B, Wf2B, cbn1, cbn2, cbf1, cbf2, out, sScr);
    else
        node_body<false>(hbf, res, coords, ybf, den, hagg, cacc, WoB, Wn1B, Wn2B,
                         Wf1B, Wf2B, cbn1, cbn2, cbf1, cbf2, out, sScr);
}

// ---------------------------------------------------------------------------
extern "C" void kernel_launch(void* const* d_in, const int* in_sizes, int n_in,
                              void* d_out, int out_size, void* d_ws, size_t ws_size,
                              hipStream_t stream)
{
    const void* h      = d_in[0];
    const void* coords = d_in[1];
    const void* a      = d_in[2];
    const void* y      = d_in[3];
    const void* res    = d_in[4];
    const int* src     = (const int*)d_in[5];
    const int* dst     = (const int*)d_in[6];

    char* ws = (char*)d_ws;
    int*   flag = (int*)(ws + FLAG_OFF);
    float* den  = (float*)(ws + DEN_OFF);
    float* cacc = (float*)(ws + CACC_OFF);
    float* hagg = (float*)(ws + HAGG_OFF);
    u16*   hbf  = (u16*)(ws + HBF_OFF);
    u16*   ybf  = (u16*)(ws + YBF_OFF);

    // convert list: 6 biases + h + y
    CvtArgs args;
    const int cvtn[8]   = {160, 160, 160, 128, 256, 256, N_NODES*HID, N_NODES*ADY};
    const int cvtsrc[8] = {8, 10, 16, 18, 20, 22, 0, 3};
    u64 boff[8];
    u64 bo = BIAS_OFF;
    for (int i = 0; i < 6; i++) {
        boff[i] = bo;
        bo += ((u64)cvtn[i] * 2 + 15) & ~(u64)15;
    }
    boff[6] = HBF_OFF;
    boff[7] = YBF_OFF;
    for (int i = 0; i < 8; i++) {
        args.src[i] = d_in[cvtsrc[i]];
        args.dstoff[i] = boff[i];
        args.n[i] = cvtn[i];
    }
    const u16* cbe1 = (const u16*)(ws + boff[0]);
    const u16* cbe2 = (const u16*)(ws + boff[1]);
    const u16* cbn1 = (const u16*)(ws + boff[2]);
    const u16* cbn2 = (const u16*)(ws + boff[3]);
    const u16* cbf1 = (const u16*)(ws + boff[4]);
    const u16* cbf2 = (const u16*)(ws + boff[5]);

    // blocked weights
    BwArgs bwa;
    bwa.We1 = d_in[7];  bwa.We2 = d_in[9];  bwa.Wv = d_in[12]; bwa.Wa = d_in[13];
    bwa.Wc  = d_in[11]; bwa.Wo  = d_in[14]; bwa.Wn1 = d_in[15]; bwa.Wn2 = d_in[17];
    bwa.Wf1 = d_in[19]; bwa.Wf2 = d_in[21];
    bwa.b1 = BW_OFF;
    bwa.b2 = bwa.b1 + (u64)5*160*72*2;
    bwa.b3 = bwa.b2 + (u64)3*160*72*2;
    bwa.b4 = bwa.b3 + (u64)3*144*72*2;
    bwa.b5 = bwa.b4 + (u64)2*128*72*2;
    bwa.b6 = bwa.b5 + (u64)2*160*72*2;
    bwa.b7 = bwa.b6 + (u64)3*128*72*2;
    bwa.b8 = bwa.b7 + (u64)256*72*2;
    const u16* We1Tb = (const u16*)(ws + bwa.b1);
    const u16* We2Tb = (const u16*)(ws + bwa.b2);
    const u16* W3Tb  = (const u16*)(ws + bwa.b3);
    const u16* WoB   = (const u16*)(ws + bwa.b4);
    const u16* Wn1B  = (const u16*)(ws + bwa.b5);
    const u16* Wn2B  = (const u16*)(ws + bwa.b6);
    const u16* Wf1B  = (const u16*)(ws + bwa.b7);
    const u16* Wf2B  = (const u16*)(ws + bwa.b8);

    hipMemsetAsync(d_ws, 0, MEMSET_BYTES, stream);

    preproc_kernel<<<256, 256, 0, stream>>>(h, flag, ws, args, bwa);

    edge_kernel<<<N_EDGES/64, 256, 0, stream>>>(flag, hbf, coords, a, src, dst,
                                                We1Tb, We2Tb, W3Tb, cbe1, cbe2,
                                                den, hagg, cacc);

    node_kernel<<<(N_NODES + 63)/64, 256, 0, stream>>>(
        flag, hbf, res, coords, ybf, den, hagg, cacc,
        WoB, Wn1B, Wn2B, Wf1B, Wf2B, cbn1, cbn2, cbf1, cbf2, d_out);
}

// Round 11
// 528.967 us; speedup vs baseline: 1.1127x; 1.0196x over previous
//
#include <hip/hip_runtime.h>
#include <math.h>

#define N_NODES 25000
#define N_EDGES 400000
#define HID 128
#define EDGE_F 16
#define ADY 64
#define INNER 160
#define MSG_F 273
#define HEADS 8

// element offsets inside d_out (h2 | coords | res2)
#define OUT_CRD (N_NODES * HID)
#define OUT_RES (N_NODES * (HID + 3))

// ws byte offsets (16-aligned)
#define FLAG_OFF 0
#define DEN_OFF  256
#define CACC_OFF 800256
#define HAGG_OFF 1100288
#define HBF_OFF  13900288            // h as bf16: 6.4 MB
#define YBF_OFF  20300288            // y as bf16: 3.2 MB
#define BIAS_OFF 23500288            // 6 bias tensors, bf16
#define BW_OFF   23502592            // blocked (fragment-linear) weights
#define MEMSET_BYTES 13900288

typedef unsigned short u16;
typedef unsigned int u32;
typedef unsigned long long u64;
typedef __attribute__((ext_vector_type(8))) short short8;
typedef __attribute__((ext_vector_type(4))) float f32x4;

__device__ __forceinline__ float bf2f(u16 v) {
    union { u32 u; float f; } x; x.u = ((u32)v) << 16; return x.f;
}
__device__ __forceinline__ u16 f2bf(float f) {
    union { float ff; u32 u; } x; x.ff = f;
    u32 u = x.u;
    u32 rounding = 0x7FFFu + ((u >> 16) & 1u);
    u += rounding;
    return (u16)(u >> 16);
}
__device__ __forceinline__ float silu(float z) {
    z = fminf(fmaxf(z, -30000.f), 30000.f);
    return z / (1.0f + __expf(-z));
}

template<bool F32> __device__ __forceinline__ float ldg1(const void* p, size_t i) {
    if (F32) return ((const float*)p)[i];
    return bf2f(((const u16*)p)[i]);
}
template<bool F32> __device__ __forceinline__ void stg1(void* p, size_t i, float v) {
    if (F32) ((float*)p)[i] = v;
    else     ((u16*)p)[i] = f2bf(v);
}
__device__ __forceinline__ float ldany(const void* p, size_t i, bool f32) {
    return f32 ? ((const float*)p)[i] : bf2f(((const u16*)p)[i]);
}
// wave-level LDS fence (node kernel)
__device__ __forceinline__ void wave_lds_fence() {
    __builtin_amdgcn_wave_barrier();
    __builtin_amdgcn_s_waitcnt(0xc07f);   // lgkmcnt(0) only
    __builtin_amdgcn_wave_barrier();
}

// ---------------------------------------------------------------------------
// Fused preprocessing: per-block dtype detect + cvt + fragment-linear blockw.
// Packed layout per 16x16x32 B-tile: [tile][lane][8] (lane = q*16+col reads
// its own contiguous 16 B; whole wave reads one contiguous 1 KB).
// lane l: col=l&15, q=l>>4; element j -> B[k = kbase + (l>>4)*8 + j][n = nbase + (l&15)]
// ---------------------------------------------------------------------------
struct CvtArgs {
    const void* src[8];
    u64 dstoff[8];
    int n[8];
};
struct BwArgs {
    const void* We1; const void* We2; const void* Wv; const void* Wa;
    const void* Wc;  const void* Wo;  const void* Wn1; const void* Wn2;
    const void* Wf1; const void* Wf2;
    u64 b1, b2, b3, b4, b5, b6, b7, b8;
};

__global__ __launch_bounds__(256)
void preproc_kernel(const void* hsrc, int* flag, char* ws, CvtArgs args, BwArgs bwa)
{
    __shared__ float red[256];
    __shared__ int sflag;
    const int t = threadIdx.x;
    {
        const u16* p = (const u16*)hsrc;
        float mx = 0.f;
        for (int i = 0; i < 8; i++) {
            int idx = (t * 8 + i) * 97;
            float v = fabsf(bf2f(p[idx * 2]));
            mx = fmaxf(mx, v);
        }
        red[t] = mx;
        __syncthreads();
        for (int s = 128; s > 0; s >>= 1) {
            if (t < s) red[t] = fmaxf(red[t], red[t + s]);
            __syncthreads();
        }
        if (t == 0) {
            sflag = (red[0] > 1e10f || red[0] == 0.f) ? 1 : 0;
            if (blockIdx.x == 0) flag[0] = sflag;
        }
        __syncthreads();
    }
    const bool f32 = (sflag != 0);
    const int g = blockIdx.x * 256 + t;
    const int stride = gridDim.x * 256;

    // ---- cvt: biases + h + y ----
    for (int ten = 0; ten < 8; ten++) {
        const void* s = args.src[ten];
        u16* d = (u16*)(ws + args.dstoff[ten]);
        const int n = args.n[ten];
        if (f32) {
            const float* sf = (const float*)s;
            for (int i = g; i < n; i += stride) d[i] = f2bf(sf[i]);
        } else {
            const u16* su = (const u16*)s;
            for (int i = g; i < n; i += stride) d[i] = su[i];
        }
    }

    // ---- fragment-linear blocked weights ----
    u16* b1 = (u16*)(ws + bwa.b1);
    u16* b2 = (u16*)(ws + bwa.b2);
    u16* b3 = (u16*)(ws + bwa.b3);
    u16* b4 = (u16*)(ws + bwa.b4);
    u16* b5 = (u16*)(ws + bwa.b5);
    u16* b6 = (u16*)(ws + bwa.b6);
    u16* b7 = (u16*)(ws + bwa.b7);
    u16* b8 = (u16*)(ws + bwa.b8);
    // We1P: [5c][2ks][10nt] tiles, K=320 logical (k==273 -> dup row 256)
    for (int i = g; i < 5*2*10*512; i += stride) {
        int tt = i >> 9, r = i & 511, l = r >> 3, j = r & 7;
        int c = tt / 20, ks = (tt / 10) % 2, nt = tt % 10;
        int k = c*64 + ks*32 + (l >> 4)*8 + j;
        int n = nt*16 + (l & 15);
        float v = 0.f;
        if (k < MSG_F)      v = ldany(bwa.We1, (size_t)k*INNER + n, f32);
        else if (k == 273)  v = ldany(bwa.We1, (size_t)256*INNER + n, f32);
        b1[i] = f2bf(v);
    }
    // We2P: [5 k5][10 nt], K=160
    for (int i = g; i < 5*10*512; i += stride) {
        int tt = i >> 9, r = i & 511, l = r >> 3, j = r & 7;
        int k5 = tt / 10, nt = tt % 10;
        int k = k5*32 + (l >> 4)*8 + j;
        int n = nt*16 + (l & 15);
        b2[i] = f2bf(ldany(bwa.We2, (size_t)k*INNER + n, f32));
    }
    // W3P: [5 k5][9 nt], K=160; n<128 Wv | n<136 Wa | n==136 Wc | else 0
    for (int i = g; i < 5*9*512; i += stride) {
        int tt = i >> 9, r = i & 511, l = r >> 3, j = r & 7;
        int k5 = tt / 9, nt = tt % 9;
        int k = k5*32 + (l >> 4)*8 + j;
        int n = nt*16 + (l & 15);
        float v = 0.f;
        if (n < 128)       v = ldany(bwa.Wv, (size_t)k*HID + n, f32);
        else if (n < 136)  v = ldany(bwa.Wa, (size_t)k*HEADS + (n-128), f32);
        else if (n == 136) v = ldany(bwa.Wc, (size_t)k, f32);
        b3[i] = f2bf(v);
    }
    // WoP: [4 cks][8 nt], K=128
    for (int i = g; i < 4*8*512; i += stride) {
        int tt = i >> 9, r = i & 511, l = r >> 3, j = r & 7;
        int cks = tt / 8, nt = tt % 8;
        int k = cks*32 + (l >> 4)*8 + j;
        int n = nt*16 + (l & 15);
        b4[i] = f2bf(ldany(bwa.Wo, (size_t)k*HID + n, f32));
    }
    // Wn1P: [4 cks][10 nt], K=128
    for (int i = g; i < 4*10*512; i += stride) {
        int tt = i >> 9, r = i & 511, l = r >> 3, j = r & 7;
        int cks = tt / 10, nt = tt % 10;
        int k = cks*32 + (l >> 4)*8 + j;
        int n = nt*16 + (l & 15);
        b5[i] = f2bf(ldany(bwa.Wn1, (size_t)k*INNER + n, f32));
    }
    // Wn2P: [5 k5][8 nt], K=160
    for (int i = g; i < 5*8*512; i += stride) {
        int tt = i >> 9, r = i & 511, l = r >> 3, j = r & 7;
        int k5 = tt / 8, nt = tt % 8;
        int k = k5*32 + (l >> 4)*8 + j;
        int n = nt*16 + (l & 15);
        b6[i] = f2bf(ldany(bwa.Wn2, (size_t)k*HID + n, f32));
    }
    // Wf1P / Wf2P: [2 ks][16 nt], K=64
    for (int i = g; i < 2*16*512; i += stride) {
        int tt = i >> 9, r = i & 511, l = r >> 3, j = r & 7;
        int ks = tt / 16, nt = tt % 16;
        int k = ks*32 + (l >> 4)*8 + j;
        int n = nt*16 + (l & 15);
        b7[i] = f2bf(ldany(bwa.Wf1, (size_t)k*256 + n, f32));
        b8[i] = f2bf(ldany(bwa.Wf2, (size_t)k*256 + n, f32));
    }
}

// ---------------------------------------------------------------------------
// MFMA edge kernel: R10 structure, fragment-linear B reads (1 KB contiguous
// per wave per MFMA).
// ---------------------------------------------------------------------------
template<bool F32>   // applies to coords / a only
__device__ __forceinline__ void edge_body(
    const u16* __restrict__ hbf, const void* coords, const void* a,
    const int* __restrict__ src, const int* __restrict__ dst,
    const u16* __restrict__ We1P, const u16* __restrict__ We2P,
    const u16* __restrict__ W3P,
    const u16* __restrict__ cbe1, const u16* __restrict__ cbe2,
    float* __restrict__ den, float* __restrict__ hagg, float* __restrict__ cacc,
    u16* sPool, float* sdiff, float* srad, int* ssrc, int* sdstl)
{
    const int t   = threadIdx.x;
    const int w   = t >> 6;
    const int l   = t & 63;
    const int col = l & 15;
    const int q   = l >> 4;
    const int e0  = blockIdx.x * 64;
    const int l8  = l << 3;

    u16* sF  = sPool;               // [64][360]
    u16* sM1 = sPool;               // [64][168] (aliases sF)
    u16* sM2 = sPool + 64*168;      // [64][168]

    if (t < 64) {
        int e = e0 + t;
        int s = src[e], d = dst[e];
        ssrc[t] = s; sdstl[t] = d;
        float dx = ldg1<F32>(coords, (size_t)s*3+0) - ldg1<F32>(coords, (size_t)d*3+0);
        float dy = ldg1<F32>(coords, (size_t)s*3+1) - ldg1<F32>(coords, (size_t)d*3+1);
        float dz = ldg1<F32>(coords, (size_t)s*3+2) - ldg1<F32>(coords, (size_t)d*3+2);
        sdiff[t*4+0] = dx; sdiff[t*4+1] = dy; sdiff[t*4+2] = dz;
        float r2 = dx*dx + dy*dy + dz*dz;
        srad[t] = r2;
        sdiff[t*4+3] = 1.0f / (sqrtf(r2 + 1e-5f) + 1.0f);
    }
    __syncthreads();                                    // B1

    // ---- stage ALL f chunks (4 lanes per edge, pure bf16 copies) ----
    {
        int e = t >> 2, part = t & 3;
        int node_s = ssrc[e], node_d = sdstl[e];
        #pragma unroll
        for (int c = 0; c < 4; c++) {
            int node = (c < 2) ? node_s : node_d;
            int c0 = (c & 1) * 64 + part * 16;
            const uint4* gp = (const uint4*)(hbf + (size_t)node*HID + c0);
            *(uint4*)(&sF[e*360 + c*72 + part*16])     = gp[0];
            *(uint4*)(&sF[e*360 + c*72 + part*16 + 8]) = gp[1];
        }
        if (part < 2) {
            __align__(16) u16 tmp[16];
            #pragma unroll
            for (int j = 0; j < 16; j++) tmp[j] = 0;
            if (part == 0) {
                float r2 = srad[e];
                tmp[0] = f2bf(r2);                           // kc0 = radial hi
                for (int j = 0; j < 15; j++)
                    tmp[1+j] = f2bf(ldg1<F32>(a, (size_t)(e0+e)*EDGE_F + j));
            } else {
                tmp[0] = f2bf(ldg1<F32>(a, (size_t)(e0+e)*EDGE_F + 15));
                float r2 = srad[e];
                tmp[1] = f2bf(r2 - bf2f(f2bf(r2)));          // kc17 = radial lo
            }
            *(uint4*)(&sF[e*360 + 4*72 + part*16])     = ((uint4*)tmp)[0];
            *(uint4*)(&sF[e*360 + 4*72 + part*16 + 8]) = ((uint4*)tmp)[1];
        }
    }
    __syncthreads();                                    // B2

    // ---- GEMM1: K=288 effective ----
    f32x4 acc1[10];
    #pragma unroll
    for (int nt = 0; nt < 10; nt++) {
        float v = bf2f(cbe1[nt*16 + col]);
        acc1[nt] = (f32x4){v, v, v, v};
    }
    const u16* fbase = &sF[(w*16 + col)*360];
    #pragma unroll
    for (int c = 0; c < 4; c++) {
        #pragma unroll
        for (int ks = 0; ks < 2; ks++) {
            short8 af = *(const short8*)(fbase + c*72 + ks*32 + q*8);
            const u16* B1 = We1P + (((c*2 + ks)*10) << 9) + l8;
            #pragma unroll
            for (int nt = 0; nt < 10; nt++) {
                short8 b = *(const short8*)(B1 + (nt << 9));
                acc1[nt] = __builtin_amdgcn_mfma_f32_16x16x32_bf16(af, b, acc1[nt], 0, 0, 0);
            }
        }
    }
    {   // c=4, ks=0 only
        short8 af = *(const short8*)(fbase + 4*72 + q*8);
        const u16* B1 = We1P + ((8*10) << 9) + l8;
        #pragma unroll
        for (int nt = 0; nt < 10; nt++) {
            short8 b = *(const short8*)(B1 + (nt << 9));
            acc1[nt] = __builtin_amdgcn_mfma_f32_16x16x32_bf16(af, b, acc1[nt], 0, 0, 0);
        }
    }
    __syncthreads();                                    // B3 (sF dead)
    #pragma unroll
    for (int nt = 0; nt < 10; nt++)
        #pragma unroll
        for (int r = 0; r < 4; r++)
            sM1[(w*16 + q*4 + r)*168 + nt*16 + col] = f2bf(silu(acc1[nt][r]));
    __syncthreads();                                    // B4

    // ---- GEMM2: K=160 ----
    f32x4 acc2[10];
    #pragma unroll
    for (int nt = 0; nt < 10; nt++) {
        float v = bf2f(cbe2[nt*16 + col]);
        acc2[nt] = (f32x4){v, v, v, v};
    }
    const u16* m1base = &sM1[(w*16 + col)*168];
    #pragma unroll
    for (int k5 = 0; k5 < 5; k5++) {
        short8 af = *(const short8*)(m1base + k5*32 + q*8);
        const u16* B2 = We2P + ((k5*10) << 9) + l8;
        #pragma unroll
        for (int nt = 0; nt < 10; nt++) {
            short8 b = *(const short8*)(B2 + (nt << 9));
            acc2[nt] = __builtin_amdgcn_mfma_f32_16x16x32_bf16(af, b, acc2[nt], 0, 0, 0);
        }
    }
    #pragma unroll
    for (int nt = 0; nt < 10; nt++)
        #pragma unroll
        for (int r = 0; r < 4; r++)
            sM2[(w*16 + q*4 + r)*168 + nt*16 + col] = f2bf(silu(acc2[nt][r]));
    __syncthreads();                                    // B5

    // ---- GEMM3: N=144, K=160 ----
    f32x4 acc3[9];
    #pragma unroll
    for (int nt = 0; nt < 9; nt++) acc3[nt] = (f32x4){0.f, 0.f, 0.f, 0.f};
    const u16* m2base = &sM2[(w*16 + col)*168];
    #pragma unroll
    for (int k5 = 0; k5 < 5; k5++) {
        short8 af = *(const short8*)(m2base + k5*32 + q*8);
        const u16* B3 = W3P + ((k5*9) << 9) + l8;
        #pragma unroll
        for (int nt = 0; nt < 9; nt++) {
            short8 b = *(const short8*)(B3 + (nt << 9));
            acc3[nt] = __builtin_amdgcn_mfma_f32_16x16x32_bf16(af, b, acc3[nt], 0, 0, 0);
        }
    }

    // ---- epilogue: wave-local, no barrier ----
    int dstep[4];
    #pragma unroll
    for (int r = 0; r < 4; r++) dstep[r] = sdstl[w*16 + q*4 + r];

    float exv[4] = {0.f, 0.f, 0.f, 0.f};
    if (col < 8) {           // logits: head=col
        #pragma unroll
        for (int r = 0; r < 4; r++) {
            float ex = __expf(fminf(fmaxf(acc3[8][r], -30.f), 30.f));
            exv[r] = ex;
            atomicAdd(&den[(size_t)dstep[r]*8 + col], ex);
        }
    } else if (col == 8) {   // coord scalar
        #pragma unroll
        for (int r = 0; r < 4; r++) {
            int idx = w*16 + q*4 + r;
            int dd = dstep[r];
            float invf = sdiff[idx*4 + 3];
            float lc = fminf(fmaxf(acc3[8][r], -1e6f), 1e6f) * invf;
            #pragma unroll
            for (int j = 0; j < 3; j++)
                atomicAdd(&cacc[(size_t)dd*3 + j], lc * sdiff[idx*4 + j]);
        }
    }
    #pragma unroll
    for (int nt = 0; nt < 8; nt++) {
        float ex0 = __shfl(exv[0], q*16 + nt);
        float ex1 = __shfl(exv[1], q*16 + nt);
        float ex2 = __shfl(exv[2], q*16 + nt);
        float ex3 = __shfl(exv[3], q*16 + nt);
        atomicAdd(&hagg[(size_t)dstep[0]*HID + nt*16 + col], acc3[nt][0] * ex0);
        atomicAdd(&hagg[(size_t)dstep[1]*HID + nt*16 + col], acc3[nt][1] * ex1);
        atomicAdd(&hagg[(size_t)dstep[2]*HID + nt*16 + col], acc3[nt][2] * ex2);
        atomicAdd(&hagg[(size_t)dstep[3]*HID + nt*16 + col], acc3[nt][3] * ex3);
    }
}

__global__ __launch_bounds__(256, 3)
void edge_kernel(const int* __restrict__ flag,
                 const u16* __restrict__ hbf, const void* coords, const void* a,
                 const int* __restrict__ src, const int* __restrict__ dst,
                 const u16* __restrict__ We1P, const u16* __restrict__ We2P,
                 const u16* __restrict__ W3P,
                 const u16* __restrict__ cbe1, const u16* __restrict__ cbe2,
                 float* __restrict__ den, float* __restrict__ hagg,
                 float* __restrict__ cacc)
{
    __shared__ __align__(16) u16 sPool[64*360];   // 46080 B
    __shared__ float sdiff[64*4];
    __shared__ float srad[64];
    __shared__ int   ssrc[64];
    __shared__ int   sdstl[64];
    if (*flag)
        edge_body<true>(hbf, coords, a, src, dst, We1P, We2P, W3P, cbe1, cbe2,
                        den, hagg, cacc, sPool, sdiff, srad, ssrc, sdstl);
    else
        edge_body<false>(hbf, coords, a, src, dst, We1P, We2P, W3P, cbe1, cbe2,
                         den, hagg, cacc, sPool, sdiff, srad, ssrc, sdstl);
}

// ---------------------------------------------------------------------------
// Barrier-free fused MFMA node kernel, fragment-linear B reads.
// ---------------------------------------------------------------------------
template<bool F32>   // applies to res / coords / out
__device__ __forceinline__ void node_body(
    const u16* __restrict__ hbf, const void* res, const void* coords,
    const u16* __restrict__ ybf,
    const float* __restrict__ den, const float* __restrict__ hagg,
    const float* __restrict__ cacc,
    const u16* __restrict__ WoP, const u16* __restrict__ Wn1P,
    const u16* __restrict__ Wn2P, const u16* __restrict__ Wf1P,
    const u16* __restrict__ Wf2P,
    const u16* __restrict__ cbn1, const u16* __restrict__ cbn2,
    const u16* __restrict__ cbf1, const u16* __restrict__ cbf2,
    void* out, u16* sScr)
{
    const int t = threadIdx.x;
    const int w = t >> 6, l = t & 63, col = l & 15, q = l >> 4;
    const int nodew = blockIdx.x * 64 + w * 16;
    const int mynode = nodew + col;
    const bool okA = mynode < N_NODES;
    const int l8 = l << 3;
    u16* sc = sScr + w * 16 * 168;

    int gm[4]; bool okC[4];
    #pragma unroll
    for (int r = 0; r < 4; r++) { gm[r] = nodew + q*4 + r; okC[r] = gm[r] < N_NODES; }

    f32x4 aF2[8];
    #pragma unroll
    for (int nt = 0; nt < 8; nt++) aF2[nt] = (f32x4){0.f,0.f,0.f,0.f};
    #pragma unroll
    for (int c = 0; c < 2; c++) {
        #pragma unroll
        for (int ks = 0; ks < 2; ks++) {
            const int kbase = c*64 + ks*32 + q*8;
            union { u16 s[8]; short8 v; } u;
            if (okA) {
                float dd = den[(size_t)mynode*8 + (kbase >> 4)];
                float inv = dd > 0.f ? 1.f/dd : 0.f;
                const float4* gp = (const float4*)(hagg + (size_t)mynode*HID + kbase);
                float4 v0 = gp[0], v1 = gp[1];
                u.s[0]=f2bf(v0.x*inv); u.s[1]=f2bf(v0.y*inv); u.s[2]=f2bf(v0.z*inv); u.s[3]=f2bf(v0.w*inv);
                u.s[4]=f2bf(v1.x*inv); u.s[5]=f2bf(v1.y*inv); u.s[6]=f2bf(v1.z*inv); u.s[7]=f2bf(v1.w*inv);
            } else {
                #pragma unroll
                for (int j = 0; j < 8; j++) u.s[j] = 0;
            }
            const u16* B = WoP + (((c*2 + ks)*8) << 9) + l8;
            #pragma unroll
            for (int nt = 0; nt < 8; nt++) {
                short8 b = *(const short8*)(B + (nt << 9));
                aF2[nt] = __builtin_amdgcn_mfma_f32_16x16x32_bf16(u.v, b, aF2[nt], 0, 0, 0);
            }
        }
    }

    f32x4 aFl[16];
    #pragma unroll
    for (int nt = 0; nt < 16; nt++) {
        float v = bf2f(cbf1[nt*16 + col]);
        aFl[nt] = (f32x4){v,v,v,v};
    }
    #pragma unroll
    for (int ks = 0; ks < 2; ks++) {
        short8 af;
        if (okA) af = *(const short8*)(ybf + (size_t)mynode*ADY + ks*32 + q*8);
        else { union { u16 s[8]; short8 v; } z; for (int j=0;j<8;j++) z.s[j]=0; af = z.v; }
        const u16* B = Wf1P + ((ks*16) << 9) + l8;
        #pragma unroll
        for (int nt = 0; nt < 16; nt++) {
            short8 b = *(const short8*)(B + (nt << 9));
            aFl[nt] = __builtin_amdgcn_mfma_f32_16x16x32_bf16(af, b, aFl[nt], 0, 0, 0);
        }
    }

    float h1c[8][4], r1c[8][4];
    {
        float xv[8][4], s[4], ss[4];
        #pragma unroll
        for (int r = 0; r < 4; r++) { s[r] = 0.f; ss[r] = 0.f; }
        #pragma unroll
        for (int nt = 0; nt < 8; nt++)
            #pragma unroll
            for (int r = 0; r < 4; r++) {
                float hv = okC[r] ? bf2f(hbf[(size_t)gm[r]*HID + nt*16 + col]) : 0.f;
                float x = hv + aF2[nt][r];
                xv[nt][r] = x; s[r] += x; ss[r] += x*x;
            }
        #pragma unroll
        for (int r = 0; r < 4; r++)
            for (int off = 1; off <= 8; off <<= 1) {
                s[r]  += __shfl_xor(s[r], off);
                ss[r] += __shfl_xor(ss[r], off);
            }
        #pragma unroll
        for (int r = 0; r < 4; r++) {
            float mu = s[r] * (1.f/128.f);
            float var = ss[r] * (1.f/128.f) - mu*mu;
            float rs = rsqrtf(fmaxf(var, 0.f) + 1e-5f);
            #pragma unroll
            for (int nt = 0; nt < 8; nt++) {
                float h1 = (xv[nt][r]-mu)*rs*(1.f+aFl[nt][r]) + aFl[nt+8][r];
                h1c[nt][r] = h1;
                float rv = okC[r] ? ldg1<F32>(res, (size_t)gm[r]*HID + nt*16 + col) : 0.f;
                r1c[nt][r] = rv + aF2[nt][r];
                sc[(q*4 + r)*168 + nt*16 + col] = f2bf(h1);
            }
        }
    }
    wave_lds_fence();

    f32x4 aT[10];
    #pragma unroll
    for (int nt = 0; nt < 10; nt++) {
        float v = bf2f(cbn1[nt*16 + col]);
        aT[nt] = (f32x4){v,v,v,v};
    }
    #pragma unroll
    for (int c = 0; c < 2; c++) {
        #pragma unroll
        for (int ks = 0; ks < 2; ks++) {
            short8 af = *(const short8*)(sc + col*168 + c*64 + ks*32 + q*8);
            const u16* B = Wn1P + (((c*2 + ks)*10) << 9) + l8;
            #pragma unroll
            for (int nt = 0; nt < 10; nt++) {
                short8 b = *(const short8*)(B + (nt << 9));
                aT[nt] = __builtin_amdgcn_mfma_f32_16x16x32_bf16(af, b, aT[nt], 0, 0, 0);
            }
        }
    }
    wave_lds_fence();
    #pragma unroll
    for (int nt = 0; nt < 10; nt++)
        #pragma unroll
        for (int r = 0; r < 4; r++)
            sc[(q*4 + r)*168 + nt*16 + col] = f2bf(silu(aT[nt][r]));
    wave_lds_fence();

    f32x4 aF3[8];
    #pragma unroll
    for (int nt = 0; nt < 8; nt++) {
        float v = bf2f(cbn2[nt*16 + col]);
        aF3[nt] = (f32x4){v,v,v,v};
    }
    #pragma unroll
    for (int k5 = 0; k5 < 5; k5++) {
        short8 af = *(const short8*)(sc + col*168 + k5*32 + q*8);
        const u16* B = Wn2P + ((k5*8) << 9) + l8;
        #pragma unroll
        for (int nt = 0; nt < 8; nt++) {
            short8 b = *(const short8*)(B + (nt << 9));
            aF3[nt] = __builtin_amdgcn_mfma_f32_16x16x32_bf16(af, b, aF3[nt], 0, 0, 0);
        }
    }

    #pragma unroll
    for (int nt = 0; nt < 16; nt++) {
        float v = bf2f(cbf2[nt*16 + col]);
        aFl[nt] = (f32x4){v,v,v,v};
    }
    #pragma unroll
    for (int ks = 0; ks < 2; ks++) {
        short8 af;
        if (okA) af = *(const short8*)(ybf + (size_t)mynode*ADY + ks*32 + q*8);
        else { union { u16 s[8]; short8 v; } z; for (int j=0;j<8;j++) z.s[j]=0; af = z.v; }
        const u16* B = Wf2P + ((ks*16) << 9) + l8;
        #pragma unroll
        for (int nt = 0; nt < 16; nt++) {
            short8 b = *(const short8*)(B + (nt << 9));
            aFl[nt] = __builtin_amdgcn_mfma_f32_16x16x32_bf16(af, b, aFl[nt], 0, 0, 0);
        }
    }

    {
        float xv[8][4], s[4], ss[4];
        #pragma unroll
        for (int r = 0; r < 4; r++) { s[r] = 0.f; ss[r] = 0.f; }
        #pragma unroll
        for (int nt = 0; nt < 8; nt++)
            #pragma unroll
            for (int r = 0; r < 4; r++) {
                float x = h1c[nt][r] + aF3[nt][r];
                xv[nt][r] = x; s[r] += x; ss[r] += x*x;
            }
        #pragma unroll
        for (int r = 0; r < 4; r++)
            for (int off = 1; off <= 8; off <<= 1) {
                s[r]  += __shfl_xor(s[r], off);
                ss[r] += __shfl_xor(ss[r], off);
            }
        #pragma unroll
        for (int r = 0; r < 4; r++) {
            float mu = s[r] * (1.f/128.f);
            float var = ss[r] * (1.f/128.f) - mu*mu;
            float rs = rsqrtf(fmaxf(var, 0.f) + 1e-5f);
            if (okC[r]) {
                #pragma unroll
                for (int nt = 0; nt < 8; nt++) {
                    int n = nt*16 + col;
                    float h2 = (xv[nt][r]-mu)*rs*(1.f+aFl[nt][r]) + aFl[nt+8][r];
                    stg1<F32>(out, (size_t)gm[r]*HID + n, h2);
                    stg1<F32>(out, (size_t)OUT_RES + (size_t)gm[r]*HID + n,
                              r1c[nt][r] + aF3[nt][r]);
                }
            }
        }
    }

    if (q == 0 && okA) {
        #pragma unroll
        for (int j = 0; j < 3; j++)
            stg1<F32>(out, (size_t)OUT_CRD + (size_t)mynode*3 + j,
                      ldg1<F32>(coords, (size_t)mynode*3 + j) + cacc[(size_t)mynode*3 + j]);
    }
}

__global__ __launch_bounds__(256, 2)
void node_kernel(const int* __restrict__ flag,
                 const u16* __restrict__ hbf, const void* res, const void* coords,
                 const u16* __restrict__ ybf,
                 const float* __restrict__ den, const float* __restrict__ hagg,
                 const float* __restrict__ cacc,
                 const u16* __restrict__ WoP, const u16* __restrict__ Wn1P,
                 const u16* __restrict__ Wn2P, const u16* __restrict__ Wf1P,
                 const u16* __restrict__ Wf2P,
                 const u16* __restrict__ cbn1, const u16* __restrict__ cbn2,
                 const u16* __restrict__ cbf1, const u16* __restrict__ cbf2,
                 void* out)
{
    __shared__ __align__(16) u16 sScr[4 * 16 * 168];
    if (*flag)
        node_body<true>(hbf, res, coords, ybf, den, hagg, cacc, WoP, Wn1P, Wn2P,
                        Wf1P, Wf2P, cbn1, cbn2, cbf1, cbf2, out, sScr);
    else
        node_body<false>(hbf, res, coords, ybf, den, hagg, cacc, WoP, Wn1P, Wn2P,
                         Wf1P, Wf2P, cbn1, cbn2, cbf1, cbf2, out, sScr);
}

// ---------------------------------------------------------------------------
extern "C" void kernel_launch(void* const* d_in, const int* in_sizes, int n_in,
                              void* d_out, int out_size, void* d_ws, size_t ws_size,
                              hipStream_t stream)
{
    const void* h      = d_in[0];
    const void* coords = d_in[1];
    const void* a      = d_in[2];
    const void* y      = d_in[3];
    const void* res    = d_in[4];
    const int* src     = (const int*)d_in[5];
    const int* dst     = (const int*)d_in[6];

    char* ws = (char*)d_ws;
    int*   flag = (int*)(ws + FLAG_OFF);
    float* den  = (float*)(ws + DEN_OFF);
    float* cacc = (float*)(ws + CACC_OFF);
    float* hagg = (float*)(ws + HAGG_OFF);
    u16*   hbf  = (u16*)(ws + HBF_OFF);
    u16*   ybf  = (u16*)(ws + YBF_OFF);

    // convert list: 6 biases + h + y
    CvtArgs args;
    const int cvtn[8]   = {160, 160, 160, 128, 256, 256, N_NODES*HID, N_NODES*ADY};
    const int cvtsrc[8] = {8, 10, 16, 18, 20, 22, 0, 3};
    u64 boff[8];
    u64 bo = BIAS_OFF;
    for (int i = 0; i < 6; i++) {
        boff[i] = bo;
        bo += ((u64)cvtn[i] * 2 + 15) & ~(u64)15;
    }
    boff[6] = HBF_OFF;
    boff[7] = YBF_OFF;
    for (int i = 0; i < 8; i++) {
        args.src[i] = d_in[cvtsrc[i]];
        args.dstoff[i] = boff[i];
        args.n[i] = cvtn[i];
    }
    const u16* cbe1 = (const u16*)(ws + boff[0]);
    const u16* cbe2 = (const u16*)(ws + boff[1]);
    const u16* cbn1 = (const u16*)(ws + boff[2]);
    const u16* cbn2 = (const u16*)(ws + boff[3]);
    const u16* cbf1 = (const u16*)(ws + boff[4]);
    const u16* cbf2 = (const u16*)(ws + boff[5]);

    // fragment-linear blocked weights
    BwArgs bwa;
    bwa.We1 = d_in[7];  bwa.We2 = d_in[9];  bwa.Wv = d_in[12]; bwa.Wa = d_in[13];
    bwa.Wc  = d_in[11]; bwa.Wo  = d_in[14]; bwa.Wn1 = d_in[15]; bwa.Wn2 = d_in[17];
    bwa.Wf1 = d_in[19]; bwa.Wf2 = d_in[21];
    bwa.b1 = BW_OFF;
    bwa.b2 = bwa.b1 + (u64)5*2*10*512*2;   // 102400 B
    bwa.b3 = bwa.b2 + (u64)5*10*512*2;     //  51200 B
    bwa.b4 = bwa.b3 + (u64)5*9*512*2;      //  46080 B
    bwa.b5 = bwa.b4 + (u64)4*8*512*2;      //  32768 B
    bwa.b6 = bwa.b5 + (u64)4*10*512*2;     //  40960 B
    bwa.b7 = bwa.b6 + (u64)5*8*512*2;      //  40960 B
    bwa.b8 = bwa.b7 + (u64)2*16*512*2;     //  32768 B
    const u16* We1P = (const u16*)(ws + bwa.b1);
    const u16* We2P = (const u16*)(ws + bwa.b2);
    const u16* W3P  = (const u16*)(ws + bwa.b3);
    const u16* WoP  = (const u16*)(ws + bwa.b4);
    const u16* Wn1P = (const u16*)(ws + bwa.b5);
    const u16* Wn2P = (const u16*)(ws + bwa.b6);
    const u16* Wf1P = (const u16*)(ws + bwa.b7);
    const u16* Wf2P = (const u16*)(ws + bwa.b8);

    hipMemsetAsync(d_ws, 0, MEMSET_BYTES, stream);

    preproc_kernel<<<256, 256, 0, stream>>>(h, flag, ws, args, bwa);

    edge_kernel<<<N_EDGES/64, 256, 0, stream>>>(flag, hbf, coords, a, src, dst,
                                                We1P, We2P, W3P, cbe1, cbe2,
                                                den, hagg, cacc);

    node_kernel<<<(N_NODES + 63)/64, 256, 0, stream>>>(
        flag, hbf, res, coords, ybf, den, hagg, cacc,
        WoP, Wn1P, Wn2P, Wf1P, Wf2P, cbn1, cbn2, cbf1, cbf2, d_out);
}